// Round 1
// baseline (1426.500 us; speedup 1.0000x reference)
//
#include <hip/hip_runtime.h>
#include <hip/hip_bf16.h>

#define BB 128
#define SS 32
#define NSTEP 31
#define IND 32
#define HID 128
#define HID2 256

typedef unsigned short u16;
typedef unsigned int u32;

__device__ __forceinline__ float bf2f(u16 u){ u32 x = ((u32)u) << 16; float f; __builtin_memcpy(&f, &x, 4); return f; }
__device__ __forceinline__ u16 f2bf(float f){ u32 x; __builtin_memcpy(&x, &f, 4); u32 r = x + 0x7FFFu + ((x >> 16) & 1u); return (u16)(r >> 16); }
__device__ __forceinline__ float gelu_f(float x){ return 0.5f * x * (1.0f + erff(x * 0.70710678118654752440f)); }

// block-wide sum of (x, y) over all 256 threads; result broadcast to all.
__device__ __forceinline__ void bsum2(float x, float y, float* red, int tid, float& ox, float& oy){
  #pragma unroll
  for (int off = 32; off >= 1; off >>= 1){ x += __shfl_xor(x, off); y += __shfl_xor(y, off); }
  __syncthreads();                      // protect red[] from previous use
  if ((tid & 63) == 0){ red[(tid >> 6)*2] = x; red[(tid >> 6)*2 + 1] = y; }
  __syncthreads();
  ox = red[0] + red[2] + red[4] + red[6];
  oy = red[1] + red[3] + red[5] + red[7];
}

// ---------------- prep: dX, hb (step sizes), gb (b3 . dX drift bias) ----------------
__global__ __launch_bounds__(128) void prep_misc(const float* __restrict__ path,
                                                 const float* __restrict__ ts,
                                                 const float* __restrict__ b3,
                                                 float* __restrict__ dX,
                                                 float* __restrict__ hb,
                                                 float* __restrict__ gb){
  const int b = blockIdx.x, tid = threadIdx.x;
  __shared__ float sdx[NSTEP * IND];
  for (int t = tid; t < NSTEP * IND; t += 128){
    int s = t >> 5, i = t & 31;
    float dt = ts[b*SS + s + 1] - ts[b*SS + s];
    float v = (path[(b*SS + s + 1)*IND + i] - path[(b*SS + s)*IND + i]) / dt;
    sdx[t] = v;
    dX[(b*NSTEP + s)*IND + i] = v;
  }
  if (tid < NSTEP) hb[b*NSTEP + tid] = ts[b*SS + tid + 1] - ts[b*SS + tid];
  __syncthreads();
  if (tid < HID){
    float w[IND];
    #pragma unroll
    for (int i = 0; i < IND; ++i) w[i] = b3[tid*IND + i];
    for (int s = 0; s < NSTEP; ++s){
      float a = 0.f;
      #pragma unroll
      for (int i = 0; i < IND; ++i) a = fmaf(w[i], sdx[s*IND + i], a);
      gb[(b*NSTEP + s)*HID + tid] = a;
    }
  }
}

// ---------------- convert vf_W1 / vf_W2 to bf16 in workspace ----------------
__global__ __launch_bounds__(256) void convw(const float* __restrict__ W1,
                                             const float* __restrict__ W2,
                                             u16* __restrict__ w1b,
                                             u16* __restrict__ w2b){
  int i = blockIdx.x*256 + threadIdx.x;
  if (i < HID*HID2) w1b[i] = f2bf(W1[i]);
  if (i < HID2*HID2) w2b[i] = f2bf(W2[i]);
}

// ---------------- G[b,s,k,h] = sum_i W3[k, h*32+i] * dX[b,s,i]  (bf16 out) ----------------
// grid: (64 col-groups of 512 cols, chunk_steps); block 256 thr; each thread owns cols (2t, 2t+1)
__global__ __launch_bounds__(256) void gprep(const float* __restrict__ W3,
                                             const float* __restrict__ dX,
                                             u16* __restrict__ G,
                                             int s0){
  const int tid = threadIdx.x;
  const int sl = blockIdx.y;
  const int s = s0 + sl;
  const int c0 = blockIdx.x*512 + tid*2;     // col = k*128 + h
  const int k = c0 >> 7, h = c0 & 127;       // h even; cols (k,h) and (k,h+1)
  const float* wp = W3 + (size_t)k*4096 + h*IND;  // 64 contiguous floats
  float4 w[16];
  #pragma unroll
  for (int i = 0; i < 16; ++i) w[i] = ((const float4*)wp)[i];
  __shared__ float sdx[BB * IND];
  for (int t = tid; t < BB * IND; t += 256){
    int bb = t >> 5, i = t & 31;
    sdx[t] = dX[(bb*NSTEP + s)*IND + i];
  }
  __syncthreads();
  u32* Gout = (u32*)G;
  const size_t rowbase = (size_t)sl * BB;
  const size_t colu = (size_t)blockIdx.x*256 + tid;
  for (int bb = 0; bb < BB; ++bb){
    const float4* dxp = (const float4*)&sdx[bb*IND];
    float a0 = 0.f, a1v = 0.f;
    #pragma unroll
    for (int i = 0; i < 8; ++i){
      float4 d = dxp[i];
      float4 wa = w[i], wb = w[i + 8];
      a0  = fmaf(d.x, wa.x, a0);  a0  = fmaf(d.y, wa.y, a0);
      a0  = fmaf(d.z, wa.z, a0);  a0  = fmaf(d.w, wa.w, a0);
      a1v = fmaf(d.x, wb.x, a1v); a1v = fmaf(d.y, wb.y, a1v);
      a1v = fmaf(d.z, wb.z, a1v); a1v = fmaf(d.w, wb.w, a1v);
    }
    u32 pk = (u32)f2bf(a0) | ((u32)f2bf(a1v) << 16);
    Gout[(rowbase + bb)*16384 + colu] = pk;
  }
}

// ---------------- sequential RK4 scan: one block per batch element ----------------
struct ScanP {
  const float *path;
  const float *eW1,*eb1,*eg1,*ebt1,*eW2,*eb2,*eg2,*ebt2;
  const u16 *w1b; const float *b1,*g1,*bt1;
  const u16 *w2b; const float *b2,*g2,*bt2;
  const float *Wv,*bv,*Wo,*bo,*dW1,*db1,*dW2,*db2;
  const float *hb,*gb;
  const u16 *G;
  float *zstate, *out;
  int s0, s1, do_enc, do_epi;
};

__global__ __launch_bounds__(256) void scan_kernel(ScanP p){
  const int tid = threadIdx.x;
  const int b = blockIdx.x;
  __shared__ float zcur[HID], zst[HID], ksum[HID], a1[HID2], a2[HID2], dr[HID2], red[8];
  float mu, sq, var, rstd;

  if (p.do_enc){
    if (tid < IND) a1[tid] = p.path[(b*SS + 0)*IND + tid];
    __syncthreads();
    float acc = 0.f;
    if (tid < HID){
      acc = p.eb1[tid];
      #pragma unroll 8
      for (int i = 0; i < IND; ++i) acc = fmaf(a1[i], p.eW1[i*HID + tid], acc);
    }
    float cx = (tid < HID) ? acc : 0.f;
    bsum2(cx, cx*cx, red, tid, mu, sq);
    mu *= (1.f/HID); var = sq*(1.f/HID) - mu*mu; rstd = rsqrtf(var + 1e-5f);
    if (tid < HID) a2[tid] = gelu_f((acc - mu)*rstd*p.eg1[tid] + p.ebt1[tid]);
    __syncthreads();
    float acc2 = 0.f;
    if (tid < HID){
      acc2 = p.eb2[tid];
      #pragma unroll 8
      for (int h = 0; h < HID; ++h) acc2 = fmaf(a2[h], p.eW2[h*HID + tid], acc2);
    }
    cx = (tid < HID) ? acc2 : 0.f;
    bsum2(cx, cx*cx, red, tid, mu, sq);
    mu *= (1.f/HID); var = sq*(1.f/HID) - mu*mu; rstd = rsqrtf(var + 1e-5f);
    if (tid < HID) zcur[tid] = (acc2 - mu)*rstd*p.eg2[tid] + p.ebt2[tid];
    __syncthreads();
  } else {
    if (tid < HID) zcur[tid] = p.zstate[b*HID + tid];
    __syncthreads();
  }

  const float rb1 = p.b1[tid], rg1 = p.g1[tid], rbt1 = p.bt1[tid];
  const float rb2 = p.b2[tid], rg2 = p.g2[tid], rbt2 = p.bt2[tid];
  const int h3 = tid & (HID-1), hf = tid >> 7;

  for (int s = p.s0; s < p.s1; ++s){
    const float hbv = p.hb[b*NSTEP + s];
    const u16* __restrict__ Gr = p.G + ((size_t)(s - p.s0)*BB + b)*((size_t)HID2*HID);
    const float* __restrict__ gbr = p.gb + (b*NSTEP + s)*HID;
    if (tid < HID){ ksum[tid] = 0.f; zst[tid] = zcur[tid]; }
    __syncthreads();
    for (int st = 0; st < 4; ++st){
      // layer1: 256 outputs, K=128
      float acc = rb1;
      #pragma unroll 16
      for (int h = 0; h < HID; ++h) acc = fmaf(zst[h], bf2f(p.w1b[h*HID2 + tid]), acc);
      bsum2(acc, acc*acc, red, tid, mu, sq);
      mu *= (1.f/HID2); var = sq*(1.f/HID2) - mu*mu; rstd = rsqrtf(var + 1e-5f);
      a1[tid] = gelu_f((acc - mu)*rstd*rg1 + rbt1);
      __syncthreads();
      // layer2: 256 outputs, K=256
      float acc2 = rb2;
      #pragma unroll 16
      for (int k = 0; k < HID2; ++k) acc2 = fmaf(a1[k], bf2f(p.w2b[k*HID2 + tid]), acc2);
      bsum2(acc2, acc2*acc2, red, tid, mu, sq);
      mu *= (1.f/HID2); var = sq*(1.f/HID2) - mu*mu; rstd = rsqrtf(var + 1e-5f);
      a2[tid] = gelu_f((acc2 - mu)*rstd*rg2 + rbt2);
      __syncthreads();
      // layer3: drift[h] = sum_k h2[k]*G[k,h]; 2 threads per h (k halves)
      const u16* __restrict__ gcol = Gr + (size_t)hf*16384 + h3;
      const float* ap = &a2[hf << 7];
      float d = 0.f;
      #pragma unroll 16
      for (int kk = 0; kk < 128; ++kk) d = fmaf(ap[kk], bf2f(gcol[(size_t)kk*HID]), d);
      dr[tid] = d;
      __syncthreads();
      if (tid < HID){
        float kv = dr[tid] + dr[tid + HID] + gbr[tid];
        ksum[tid] += ((st == 0 || st == 3) ? 1.f : 2.f)*kv;
        if (st == 0)      zst[tid] = zcur[tid] + 0.5f*hbv*kv;
        else if (st == 1) zst[tid] = zcur[tid] + 0.5f*hbv*kv;
        else if (st == 2) zst[tid] = zcur[tid] + hbv*kv;
      }
      __syncthreads();
    }
    if (tid < HID) zcur[tid] += hbv*(1.f/6.f)*ksum[tid];
    __syncthreads();
  }

  if (p.do_epi){
    if (tid < HID){
      float v = p.bv[tid];
      #pragma unroll 8
      for (int h = 0; h < HID; ++h) v = fmaf(zcur[h], p.Wv[h*HID + tid], v);
      a1[tid] = v;
    }
    __syncthreads();
    if (tid < HID){
      float f = p.bo[tid];
      #pragma unroll 8
      for (int h = 0; h < HID; ++h) f = fmaf(a1[h], p.Wo[h*HID + tid], f);
      a2[tid] = f;
    }
    __syncthreads();
    if (tid < HID){
      float hd = p.db1[tid];
      #pragma unroll 8
      for (int h = 0; h < HID; ++h) hd = fmaf(a2[h], p.dW1[h*HID + tid], hd);
      dr[tid] = gelu_f(hd);
    }
    __syncthreads();
    if (tid < 10){
      float t = p.db2[tid];
      #pragma unroll 8
      for (int h = 0; h < HID; ++h) t = fmaf(dr[h], p.dW2[h*10 + tid], t);
      p.out[b*10 + tid] = t;
    }
    if (tid == 0) p.out[BB*10 + b] = 1.0f;   // attention weights are exactly 1.0
  } else {
    if (tid < HID) p.zstate[b*HID + tid] = zcur[tid];
  }
}

extern "C" void kernel_launch(void* const* d_in, const int* in_sizes, int n_in,
                              void* d_out, int out_size, void* d_ws, size_t ws_size,
                              hipStream_t stream){
  const float* path  = (const float*)d_in[0];
  const float* ts    = (const float*)d_in[1];
  const float* eW1   = (const float*)d_in[2];
  const float* eb1   = (const float*)d_in[3];
  const float* eg1   = (const float*)d_in[4];
  const float* ebt1  = (const float*)d_in[5];
  const float* eW2   = (const float*)d_in[6];
  const float* eb2   = (const float*)d_in[7];
  const float* eg2   = (const float*)d_in[8];
  const float* ebt2  = (const float*)d_in[9];
  const float* vW1   = (const float*)d_in[10];
  const float* vb1   = (const float*)d_in[11];
  const float* vg1   = (const float*)d_in[12];
  const float* vbt1  = (const float*)d_in[13];
  const float* vW2   = (const float*)d_in[14];
  const float* vb2   = (const float*)d_in[15];
  const float* vg2   = (const float*)d_in[16];
  const float* vbt2  = (const float*)d_in[17];
  const float* vW3   = (const float*)d_in[18];
  const float* vb3   = (const float*)d_in[19];
  const float* Wv    = (const float*)d_in[24];
  const float* bv    = (const float*)d_in[25];
  const float* Wo    = (const float*)d_in[26];
  const float* bo    = (const float*)d_in[27];
  const float* dW1   = (const float*)d_in[28];
  const float* db1   = (const float*)d_in[29];
  const float* dW2   = (const float*)d_in[30];
  const float* db2   = (const float*)d_in[31];

  char* wsb = (char*)d_ws;
  float* z_state = (float*)(wsb + 0);            // 64 KB
  float* dX  = (float*)(wsb + 65536);            // 496 KB
  float* hb  = (float*)(wsb + 573440);           // 15.5 KB
  float* gb  = (float*)(wsb + 589312);           // 1.9 MB
  u16*   w1b = (u16*)(wsb + 2620928);            // 64 KB
  u16*   w2b = (u16*)(wsb + 2686464);            // 128 KB
  u16*   G   = (u16*)(wsb + 2817536);            // up to 248 MB

  hipLaunchKernelGGL(prep_misc, dim3(BB), dim3(128), 0, stream, path, ts, vb3, dX, hb, gb);
  hipLaunchKernelGGL(convw, dim3(256), dim3(256), 0, stream, vW1, vW2, w1b, w2b);

  const size_t per_step = (size_t)BB * HID2 * HID * 2;   // 8 MB per step, bf16
  size_t gav = (ws_size > 2817536) ? (ws_size - 2817536) : per_step;
  int chunk = (int)(gav / per_step);
  if (chunk < 1) chunk = 1;
  if (chunk > NSTEP) chunk = NSTEP;

  for (int s0 = 0; s0 < NSTEP; s0 += chunk){
    int cs = (NSTEP - s0 < chunk) ? (NSTEP - s0) : chunk;
    hipLaunchKernelGGL(gprep, dim3(64, cs), dim3(256), 0, stream, vW3, dX, G, s0);
    ScanP P;
    P.path = path;
    P.eW1 = eW1; P.eb1 = eb1; P.eg1 = eg1; P.ebt1 = ebt1;
    P.eW2 = eW2; P.eb2 = eb2; P.eg2 = eg2; P.ebt2 = ebt2;
    P.w1b = w1b; P.b1 = vb1; P.g1 = vg1; P.bt1 = vbt1;
    P.w2b = w2b; P.b2 = vb2; P.g2 = vg2; P.bt2 = vbt2;
    P.Wv = Wv; P.bv = bv; P.Wo = Wo; P.bo = bo;
    P.dW1 = dW1; P.db1 = db1; P.dW2 = dW2; P.db2 = db2;
    P.hb = hb; P.gb = gb; P.G = G;
    P.zstate = z_state; P.out = (float*)d_out;
    P.s0 = s0; P.s1 = s0 + cs;
    P.do_enc = (s0 == 0) ? 1 : 0;
    P.do_epi = (s0 + cs == NSTEP) ? 1 : 0;
    hipLaunchKernelGGL(scan_kernel, dim3(BB), dim3(256), 0, stream, P);
  }
}

// Round 2
// 1351.973 us; speedup vs baseline: 1.0551x; 1.0551x over previous
//
#include <hip/hip_runtime.h>
#include <hip/hip_bf16.h>

#define BB 128
#define SS 32
#define NSTEP 31
#define IND 32
#define HID 128
#define HID2 256

typedef unsigned short u16;
typedef unsigned int u32;

__device__ __forceinline__ float bf2f(u16 u){ u32 x = ((u32)u) << 16; float f; __builtin_memcpy(&f, &x, 4); return f; }
__device__ __forceinline__ float bflo(u32 p){ u32 x = p << 16; float f; __builtin_memcpy(&f, &x, 4); return f; }
__device__ __forceinline__ float bfhi(u32 p){ u32 x = p & 0xffff0000u; float f; __builtin_memcpy(&f, &x, 4); return f; }
__device__ __forceinline__ u16 f2bf(float f){ u32 x; __builtin_memcpy(&x, &f, 4); u32 r = x + 0x7FFFu + ((x >> 16) & 1u); return (u16)(r >> 16); }
__device__ __forceinline__ float gelu_f(float x){ return 0.5f * x * (1.0f + erff(x * 0.70710678118654752440f)); }

// block-wide sum of (x, y) over all 256 threads; result broadcast to all.
__device__ __forceinline__ void bsum2(float x, float y, float* red, int tid, float& ox, float& oy){
  #pragma unroll
  for (int off = 32; off >= 1; off >>= 1){ x += __shfl_xor(x, off); y += __shfl_xor(y, off); }
  __syncthreads();                      // protect red[] from previous use
  if ((tid & 63) == 0){ red[(tid >> 6)*2] = x; red[(tid >> 6)*2 + 1] = y; }
  __syncthreads();
  ox = red[0] + red[2] + red[4] + red[6];
  oy = red[1] + red[3] + red[5] + red[7];
}

// ---------------- prep: dX, hb (step sizes), gb (b3 . dX drift bias) ----------------
__global__ __launch_bounds__(128) void prep_misc(const float* __restrict__ path,
                                                 const float* __restrict__ ts,
                                                 const float* __restrict__ b3,
                                                 float* __restrict__ dX,
                                                 float* __restrict__ hb,
                                                 float* __restrict__ gb){
  const int b = blockIdx.x, tid = threadIdx.x;
  __shared__ float sdx[NSTEP * IND];
  for (int t = tid; t < NSTEP * IND; t += 128){
    int s = t >> 5, i = t & 31;
    float dt = ts[b*SS + s + 1] - ts[b*SS + s];
    float v = (path[(b*SS + s + 1)*IND + i] - path[(b*SS + s)*IND + i]) / dt;
    sdx[t] = v;
    dX[(b*NSTEP + s)*IND + i] = v;
  }
  if (tid < NSTEP) hb[b*NSTEP + tid] = ts[b*SS + tid + 1] - ts[b*SS + tid];
  __syncthreads();
  if (tid < HID){
    float w[IND];
    #pragma unroll
    for (int i = 0; i < IND; ++i) w[i] = b3[tid*IND + i];
    for (int s = 0; s < NSTEP; ++s){
      float a = 0.f;
      #pragma unroll
      for (int i = 0; i < IND; ++i) a = fmaf(w[i], sdx[s*IND + i], a);
      gb[(b*NSTEP + s)*HID + tid] = a;
    }
  }
}

// ---------------- G[b,s,k,h] = sum_i W3[k, h*32+i] * dX[b,s,i]  (bf16 out) ----------------
// grid: (64 col-groups of 512 cols, chunk_steps); block 256 thr; each thread owns cols (2t, 2t+1)
__global__ __launch_bounds__(256) void gprep(const float* __restrict__ W3,
                                             const float* __restrict__ dX,
                                             u16* __restrict__ G,
                                             int s0){
  const int tid = threadIdx.x;
  const int sl = blockIdx.y;
  const int s = s0 + sl;
  const int c0 = blockIdx.x*512 + tid*2;     // col = k*128 + h
  const int k = c0 >> 7, h = c0 & 127;       // h even; cols (k,h) and (k,h+1)
  const float* wp = W3 + (size_t)k*4096 + h*IND;  // 64 contiguous floats
  float4 w[16];
  #pragma unroll
  for (int i = 0; i < 16; ++i) w[i] = ((const float4*)wp)[i];
  __shared__ float sdx[BB * IND];
  for (int t = tid; t < BB * IND; t += 256){
    int bb = t >> 5, i = t & 31;
    sdx[t] = dX[(bb*NSTEP + s)*IND + i];
  }
  __syncthreads();
  u32* Gout = (u32*)G;
  const size_t rowbase = (size_t)sl * BB;
  const size_t colu = (size_t)blockIdx.x*256 + tid;
  for (int bb = 0; bb < BB; ++bb){
    const float4* dxp = (const float4*)&sdx[bb*IND];
    float a0a = 0.f, a0b = 0.f, a1a = 0.f, a1b = 0.f;
    #pragma unroll
    for (int i = 0; i < 4; ++i){
      float4 d = dxp[i];
      float4 wa = w[i], wb = w[i + 8];
      a0a = fmaf(d.x, wa.x, a0a); a0a = fmaf(d.y, wa.y, a0a);
      a0a = fmaf(d.z, wa.z, a0a); a0a = fmaf(d.w, wa.w, a0a);
      a1a = fmaf(d.x, wb.x, a1a); a1a = fmaf(d.y, wb.y, a1a);
      a1a = fmaf(d.z, wb.z, a1a); a1a = fmaf(d.w, wb.w, a1a);
    }
    #pragma unroll
    for (int i = 4; i < 8; ++i){
      float4 d = dxp[i];
      float4 wa = w[i], wb = w[i + 8];
      a0b = fmaf(d.x, wa.x, a0b); a0b = fmaf(d.y, wa.y, a0b);
      a0b = fmaf(d.z, wa.z, a0b); a0b = fmaf(d.w, wa.w, a0b);
      a1b = fmaf(d.x, wb.x, a1b); a1b = fmaf(d.y, wb.y, a1b);
      a1b = fmaf(d.z, wb.z, a1b); a1b = fmaf(d.w, wb.w, a1b);
    }
    u32 pk = (u32)f2bf(a0a + a0b) | ((u32)f2bf(a1a + a1b) << 16);
    Gout[(rowbase + bb)*16384 + colu] = pk;
  }
}

// ---------------- sequential RK4 scan: one block per batch element ----------------
struct ScanP {
  const float *path;
  const float *eW1,*eb1,*eg1,*ebt1,*eW2,*eb2,*eg2,*ebt2;
  const float *vW1; const float *b1,*g1,*bt1;
  const float *vW2; const float *b2,*g2,*bt2;
  const float *Wv,*bv,*Wo,*bo,*dW1,*db1,*dW2,*db2;
  const float *hb,*gb;
  const u16 *G;
  float *zstate, *out;
  int s0, s1, do_enc, do_epi;
};

__global__ __launch_bounds__(256, 1) void scan_kernel(ScanP p){
  const int tid = threadIdx.x;
  const int b = blockIdx.x;
  __shared__ __align__(16) float zcur[HID];
  __shared__ __align__(16) float zst[HID];
  __shared__ __align__(16) float ksum[HID];
  __shared__ __align__(16) float a1[HID2];
  __shared__ __align__(16) float a2[HID2];
  __shared__ __align__(16) float dr[HID2];
  __shared__ float red[8];
  float mu, sq, var, rstd;

  // ---- persistent per-thread weight registers ----
  float w1c[HID];                    // fp32 column of vf_W1 (128 regs)
  #pragma unroll
  for (int h = 0; h < HID; ++h) w1c[h] = p.vW1[h*HID2 + tid];
  u32 w2p[HID2/2];                   // packed bf16 column of vf_W2 (128 regs)
  #pragma unroll
  for (int j = 0; j < HID2/2; ++j){
    float lo = p.vW2[(2*j)*HID2 + tid];
    float hi = p.vW2[(2*j+1)*HID2 + tid];
    w2p[j] = (u32)f2bf(lo) | ((u32)f2bf(hi) << 16);
  }

  if (p.do_enc){
    if (tid < IND) a1[tid] = p.path[(b*SS + 0)*IND + tid];
    __syncthreads();
    float acc = 0.f;
    if (tid < HID){
      acc = p.eb1[tid];
      #pragma unroll 8
      for (int i = 0; i < IND; ++i) acc = fmaf(a1[i], p.eW1[i*HID + tid], acc);
    }
    float cx = (tid < HID) ? acc : 0.f;
    bsum2(cx, cx*cx, red, tid, mu, sq);
    mu *= (1.f/HID); var = sq*(1.f/HID) - mu*mu; rstd = rsqrtf(var + 1e-5f);
    if (tid < HID) a2[tid] = gelu_f((acc - mu)*rstd*p.eg1[tid] + p.ebt1[tid]);
    __syncthreads();
    float acc2 = 0.f;
    if (tid < HID){
      acc2 = p.eb2[tid];
      #pragma unroll 8
      for (int h = 0; h < HID; ++h) acc2 = fmaf(a2[h], p.eW2[h*HID + tid], acc2);
    }
    cx = (tid < HID) ? acc2 : 0.f;
    bsum2(cx, cx*cx, red, tid, mu, sq);
    mu *= (1.f/HID); var = sq*(1.f/HID) - mu*mu; rstd = rsqrtf(var + 1e-5f);
    if (tid < HID) zcur[tid] = (acc2 - mu)*rstd*p.eg2[tid] + p.ebt2[tid];
    __syncthreads();
  } else {
    if (tid < HID) zcur[tid] = p.zstate[b*HID + tid];
    __syncthreads();
  }

  const float rb1 = p.b1[tid], rg1 = p.g1[tid], rbt1 = p.bt1[tid];
  const float rb2 = p.b2[tid], rg2 = p.g2[tid], rbt2 = p.bt2[tid];
  const int h3 = tid & (HID-1), hf = tid >> 7;

  for (int s = p.s0; s < p.s1; ++s){
    const float hbv = p.hb[b*NSTEP + s];
    const float* __restrict__ gbr = p.gb + (b*NSTEP + s)*HID;
    // ---- prefetch this step's G column into registers (consumed ~layer1+layer2 later) ----
    const u16* __restrict__ gcol = p.G + ((size_t)(s - p.s0)*BB + b)*((size_t)HID2*HID)
                                       + (size_t)hf*16384 + h3;
    u16 gk[128];
    #pragma unroll
    for (int j = 0; j < 128; ++j) gk[j] = gcol[(size_t)j*HID];

    if (tid < HID){ ksum[tid] = 0.f; zst[tid] = zcur[tid]; }
    __syncthreads();
    for (int st = 0; st < 4; ++st){
      // ---- layer1: 256 outputs, K=128, weights in fp32 regs ----
      float c0 = 0.f, c1 = 0.f, c2 = 0.f, c3 = 0.f;
      #pragma unroll
      for (int h = 0; h < HID; h += 4){
        float4 z4 = *(const float4*)&zst[h];
        c0 = fmaf(z4.x, w1c[h],   c0);
        c1 = fmaf(z4.y, w1c[h+1], c1);
        c2 = fmaf(z4.z, w1c[h+2], c2);
        c3 = fmaf(z4.w, w1c[h+3], c3);
      }
      float acc = rb1 + ((c0 + c1) + (c2 + c3));
      bsum2(acc, acc*acc, red, tid, mu, sq);
      mu *= (1.f/HID2); var = sq*(1.f/HID2) - mu*mu; rstd = rsqrtf(var + 1e-5f);
      a1[tid] = gelu_f((acc - mu)*rstd*rg1 + rbt1);
      __syncthreads();
      // ---- layer2: 256 outputs, K=256, weights packed bf16 in regs ----
      c0 = 0.f; c1 = 0.f; c2 = 0.f; c3 = 0.f;
      #pragma unroll
      for (int j = 0; j < HID2/2; j += 2){
        float4 a4 = *(const float4*)&a1[2*j];
        u32 p0 = w2p[j], p1 = w2p[j+1];
        c0 = fmaf(a4.x, bflo(p0), c0);
        c1 = fmaf(a4.y, bfhi(p0), c1);
        c2 = fmaf(a4.z, bflo(p1), c2);
        c3 = fmaf(a4.w, bfhi(p1), c3);
      }
      float acc2 = rb2 + ((c0 + c1) + (c2 + c3));
      bsum2(acc2, acc2*acc2, red, tid, mu, sq);
      mu *= (1.f/HID2); var = sq*(1.f/HID2) - mu*mu; rstd = rsqrtf(var + 1e-5f);
      a2[tid] = gelu_f((acc2 - mu)*rstd*rg2 + rbt2);
      __syncthreads();
      // ---- layer3: drift halves from register-resident G ----
      c0 = 0.f; c1 = 0.f; c2 = 0.f; c3 = 0.f;
      const float* ap = &a2[hf << 7];
      #pragma unroll
      for (int kk = 0; kk < 128; kk += 4){
        float4 a4 = *(const float4*)&ap[kk];
        c0 = fmaf(a4.x, bf2f(gk[kk]),   c0);
        c1 = fmaf(a4.y, bf2f(gk[kk+1]), c1);
        c2 = fmaf(a4.z, bf2f(gk[kk+2]), c2);
        c3 = fmaf(a4.w, bf2f(gk[kk+3]), c3);
      }
      dr[tid] = (c0 + c1) + (c2 + c3);
      __syncthreads();
      if (tid < HID){
        float kv = dr[tid] + dr[tid + HID] + gbr[tid];
        ksum[tid] += ((st == 0 || st == 3) ? 1.f : 2.f)*kv;
        if (st == 0)      zst[tid] = zcur[tid] + 0.5f*hbv*kv;
        else if (st == 1) zst[tid] = zcur[tid] + 0.5f*hbv*kv;
        else if (st == 2) zst[tid] = zcur[tid] + hbv*kv;
      }
      __syncthreads();
    }
    if (tid < HID) zcur[tid] += hbv*(1.f/6.f)*ksum[tid];
    __syncthreads();
  }

  if (p.do_epi){
    if (tid < HID){
      float v = p.bv[tid];
      #pragma unroll 8
      for (int h = 0; h < HID; ++h) v = fmaf(zcur[h], p.Wv[h*HID + tid], v);
      a1[tid] = v;
    }
    __syncthreads();
    if (tid < HID){
      float f = p.bo[tid];
      #pragma unroll 8
      for (int h = 0; h < HID; ++h) f = fmaf(a1[h], p.Wo[h*HID + tid], f);
      a2[tid] = f;
    }
    __syncthreads();
    if (tid < HID){
      float hd = p.db1[tid];
      #pragma unroll 8
      for (int h = 0; h < HID; ++h) hd = fmaf(a2[h], p.dW1[h*HID + tid], hd);
      dr[tid] = gelu_f(hd);
    }
    __syncthreads();
    if (tid < 10){
      float t = p.db2[tid];
      #pragma unroll 8
      for (int h = 0; h < HID; ++h) t = fmaf(dr[h], p.dW2[h*10 + tid], t);
      p.out[b*10 + tid] = t;
    }
    if (tid == 0) p.out[BB*10 + b] = 1.0f;   // attention weights are exactly 1.0
  } else {
    if (tid < HID) p.zstate[b*HID + tid] = zcur[tid];
  }
}

extern "C" void kernel_launch(void* const* d_in, const int* in_sizes, int n_in,
                              void* d_out, int out_size, void* d_ws, size_t ws_size,
                              hipStream_t stream){
  const float* path  = (const float*)d_in[0];
  const float* ts    = (const float*)d_in[1];
  const float* eW1   = (const float*)d_in[2];
  const float* eb1   = (const float*)d_in[3];
  const float* eg1   = (const float*)d_in[4];
  const float* ebt1  = (const float*)d_in[5];
  const float* eW2   = (const float*)d_in[6];
  const float* eb2   = (const float*)d_in[7];
  const float* eg2   = (const float*)d_in[8];
  const float* ebt2  = (const float*)d_in[9];
  const float* vW1   = (const float*)d_in[10];
  const float* vb1   = (const float*)d_in[11];
  const float* vg1   = (const float*)d_in[12];
  const float* vbt1  = (const float*)d_in[13];
  const float* vW2   = (const float*)d_in[14];
  const float* vb2   = (const float*)d_in[15];
  const float* vg2   = (const float*)d_in[16];
  const float* vbt2  = (const float*)d_in[17];
  const float* vW3   = (const float*)d_in[18];
  const float* vb3   = (const float*)d_in[19];
  const float* Wv    = (const float*)d_in[24];
  const float* bv    = (const float*)d_in[25];
  const float* Wo    = (const float*)d_in[26];
  const float* bo    = (const float*)d_in[27];
  const float* dW1   = (const float*)d_in[28];
  const float* db1   = (const float*)d_in[29];
  const float* dW2   = (const float*)d_in[30];
  const float* db2   = (const float*)d_in[31];

  char* wsb = (char*)d_ws;
  float* z_state = (float*)(wsb + 0);            // 64 KB
  float* dX  = (float*)(wsb + 65536);            // 496 KB
  float* hb  = (float*)(wsb + 573440);           // 15.5 KB
  float* gb  = (float*)(wsb + 589312);           // 1.9 MB
  u16*   G   = (u16*)(wsb + 2621440);            // up to 248 MB

  hipLaunchKernelGGL(prep_misc, dim3(BB), dim3(128), 0, stream, path, ts, vb3, dX, hb, gb);

  const size_t per_step = (size_t)BB * HID2 * HID * 2;   // 8 MB per step, bf16
  size_t gav = (ws_size > 2621440) ? (ws_size - 2621440) : per_step;
  int chunk = (int)(gav / per_step);
  if (chunk < 1) chunk = 1;
  if (chunk > NSTEP) chunk = NSTEP;

  for (int s0 = 0; s0 < NSTEP; s0 += chunk){
    int cs = (NSTEP - s0 < chunk) ? (NSTEP - s0) : chunk;
    hipLaunchKernelGGL(gprep, dim3(64, cs), dim3(256), 0, stream, vW3, dX, G, s0);
    ScanP P;
    P.path = path;
    P.eW1 = eW1; P.eb1 = eb1; P.eg1 = eg1; P.ebt1 = ebt1;
    P.eW2 = eW2; P.eb2 = eb2; P.eg2 = eg2; P.ebt2 = ebt2;
    P.vW1 = vW1; P.b1 = vb1; P.g1 = vg1; P.bt1 = vbt1;
    P.vW2 = vW2; P.b2 = vb2; P.g2 = vg2; P.bt2 = vbt2;
    P.Wv = Wv; P.bv = bv; P.Wo = Wo; P.bo = bo;
    P.dW1 = dW1; P.db1 = db1; P.dW2 = dW2; P.db2 = db2;
    P.hb = hb; P.gb = gb; P.G = G;
    P.zstate = z_state; P.out = (float*)d_out;
    P.s0 = s0; P.s1 = s0 + cs;
    P.do_enc = (s0 == 0) ? 1 : 0;
    P.do_epi = (s0 + cs == NSTEP) ? 1 : 0;
    hipLaunchKernelGGL(scan_kernel, dim3(BB), dim3(256), 0, stream, P);
  }
}

// Round 4
// 898.340 us; speedup vs baseline: 1.5879x; 1.5050x over previous
//
#include <hip/hip_runtime.h>
#include <hip/hip_bf16.h>

#define BB 128
#define SS 32
#define NSTEP 31
#define IND 32
#define HID 128
#define HID2 256

typedef unsigned short u16;
typedef unsigned int u32;
typedef _Float16 f16;
typedef f16 h2 __attribute__((ext_vector_type(2)));
typedef __fp16 fp16v2 __attribute__((ext_vector_type(2)));

__device__ __forceinline__ float dot2f(u32 a, u32 b, float c){
#if __has_builtin(__builtin_amdgcn_fdot2)
  h2 ha, hb; __builtin_memcpy(&ha, &a, 4); __builtin_memcpy(&hb, &b, 4);
  return __builtin_amdgcn_fdot2(ha, hb, c, false);
#else
  h2 ha, hb; __builtin_memcpy(&ha, &a, 4); __builtin_memcpy(&hb, &b, 4);
  return c + (float)ha[0]*(float)hb[0] + (float)ha[1]*(float)hb[1];
#endif
}
__device__ __forceinline__ u32 pkh2(float a, float b){
  fp16v2 r = __builtin_amdgcn_cvt_pkrtz(a, b);
  u32 u; __builtin_memcpy(&u, &r, 4); return u;
}
__device__ __forceinline__ u16 f2h(float f){ f16 h = (f16)f; u16 u; __builtin_memcpy(&u, &h, 2); return u; }
__device__ __forceinline__ float gelu_f(float x){ return 0.5f * x * (1.0f + erff(x * 0.70710678118654752440f)); }

// block-wide sum of (x,y) over 256 threads (leading sync protects red[]) — used in enc/epi only
__device__ __forceinline__ void bsum2(float x, float y, float* red, int tid, float& ox, float& oy){
  #pragma unroll
  for (int off = 32; off >= 1; off >>= 1){ x += __shfl_xor(x, off); y += __shfl_xor(y, off); }
  __syncthreads();
  if ((tid & 63) == 0){ red[(tid >> 6)*2] = x; red[(tid >> 6)*2 + 1] = y; }
  __syncthreads();
  ox = red[0] + red[2] + red[4] + red[6];
  oy = red[1] + red[3] + red[5] + red[7];
}

// ---------------- prep: dxh (packed half2 dX), hb, gb ----------------
__global__ __launch_bounds__(128) void prep_misc(const float* __restrict__ path,
                                                 const float* __restrict__ ts,
                                                 const float* __restrict__ b3,
                                                 u32* __restrict__ dxh,
                                                 float* __restrict__ hb,
                                                 float* __restrict__ gb){
  const int b = blockIdx.x, tid = threadIdx.x;
  __shared__ float sdx[NSTEP * IND];
  for (int t = tid; t < NSTEP * IND; t += 128){
    int s = t >> 5, i = t & 31;
    float dt = ts[b*SS + s + 1] - ts[b*SS + s];
    sdx[t] = (path[(b*SS + s + 1)*IND + i] - path[(b*SS + s)*IND + i]) / dt;
  }
  if (tid < NSTEP) hb[b*NSTEP + tid] = ts[b*SS + tid + 1] - ts[b*SS + tid];
  __syncthreads();
  for (int t = tid; t < NSTEP * 16; t += 128){
    int s = t >> 4, i2 = t & 15;
    dxh[((size_t)b*NSTEP + s)*16 + i2] = pkh2(sdx[s*IND + 2*i2], sdx[s*IND + 2*i2 + 1]);
  }
  if (tid < HID){
    float w[IND];
    #pragma unroll
    for (int i = 0; i < IND; ++i) w[i] = b3[tid*IND + i];
    for (int s = 0; s < NSTEP; ++s){
      float a = 0.f;
      #pragma unroll
      for (int i = 0; i < IND; ++i) a = fmaf(w[i], sdx[s*IND + i], a);
      gb[(b*NSTEP + s)*HID + tid] = a;
    }
  }
}

// ---------------- pack vf_W3 (fp32) -> half2 pairs over the i-dimension ----------------
__global__ __launch_bounds__(256) void pack_w3(const float* __restrict__ W3, u32* __restrict__ w3h){
  int i = blockIdx.x*256 + threadIdx.x;           // 524288 u32 outputs
  if (i < (HID2*HID*IND)/2) w3h[i] = pkh2(W3[2*i], W3[2*i + 1]);
}

// ---------------- G pair-packed: Gp[(sl*BB+b)*16384 + kp*128 + h] = pk(G[2kp][h], G[2kp+1][h]) ----------------
__global__ __launch_bounds__(256) void gprep_h(const u32* __restrict__ w3h,
                                               const u32* __restrict__ dxh,
                                               u32* __restrict__ Gp, int s0){
  const int tid = threadIdx.x;
  const int sl = blockIdx.y; const int s = s0 + sl;
  const int lin = blockIdx.x*256 + tid;           // 0..16383 over (kp,h)
  const int kp = lin >> 7, h = lin & 127;
  const uint4* wa = (const uint4*)(w3h + ((size_t)(2*kp)*HID + h)*16);
  const uint4* wb = (const uint4*)(w3h + ((size_t)(2*kp+1)*HID + h)*16);
  uint4 A0 = wa[0], A1 = wa[1], A2 = wa[2], A3 = wa[3];
  uint4 B0 = wb[0], B1 = wb[1], B2 = wb[2], B3 = wb[3];
  __shared__ u32 sdx[BB * 16];
  for (int t = tid; t < BB * 16; t += 256){
    int bb = t >> 4, i2 = t & 15;
    sdx[t] = dxh[((size_t)bb*NSTEP + s)*16 + i2];
  }
  __syncthreads();
  const size_t outbase = (size_t)sl * BB * 16384 + lin;
  for (int bb = 0; bb < BB; ++bb){
    const uint4* dp = (const uint4*)&sdx[bb*16];
    uint4 D0 = dp[0], D1 = dp[1], D2 = dp[2], D3 = dp[3];
    float g0 = 0.f, g1 = 0.f, g2 = 0.f, g3 = 0.f;
    g0 = dot2f(D0.x, A0.x, g0); g0 = dot2f(D0.y, A0.y, g0);
    g0 = dot2f(D0.z, A0.z, g0); g0 = dot2f(D0.w, A0.w, g0);
    g2 = dot2f(D1.x, A1.x, g2); g2 = dot2f(D1.y, A1.y, g2);
    g2 = dot2f(D1.z, A1.z, g2); g2 = dot2f(D1.w, A1.w, g2);
    g0 = dot2f(D2.x, A2.x, g0); g0 = dot2f(D2.y, A2.y, g0);
    g0 = dot2f(D2.z, A2.z, g0); g0 = dot2f(D2.w, A2.w, g0);
    g2 = dot2f(D3.x, A3.x, g2); g2 = dot2f(D3.y, A3.y, g2);
    g2 = dot2f(D3.z, A3.z, g2); g2 = dot2f(D3.w, A3.w, g2);
    g1 = dot2f(D0.x, B0.x, g1); g1 = dot2f(D0.y, B0.y, g1);
    g1 = dot2f(D0.z, B0.z, g1); g1 = dot2f(D0.w, B0.w, g1);
    g3 = dot2f(D1.x, B1.x, g3); g3 = dot2f(D1.y, B1.y, g3);
    g3 = dot2f(D1.z, B1.z, g3); g3 = dot2f(D1.w, B1.w, g3);
    g1 = dot2f(D2.x, B2.x, g1); g1 = dot2f(D2.y, B2.y, g1);
    g1 = dot2f(D2.z, B2.z, g1); g1 = dot2f(D2.w, B2.w, g1);
    g3 = dot2f(D3.x, B3.x, g3); g3 = dot2f(D3.y, B3.y, g3);
    g3 = dot2f(D3.z, B3.z, g3); g3 = dot2f(D3.w, B3.w, g3);
    Gp[outbase + (size_t)bb*16384] = pkh2(g0 + g2, g1 + g3);
  }
}

// ---------------- sequential RK4 scan: one block per batch element ----------------
struct ScanP {
  const float *path;
  const float *eW1,*eb1,*eg1,*ebt1,*eW2,*eb2,*eg2,*ebt2;
  const float *vW1,*b1,*g1,*bt1;
  const float *vW2,*b2,*g2,*bt2;
  const float *Wv,*bv,*Wo,*bo,*dW1,*db1,*dW2,*db2;
  const float *hb,*gb;
  const u32 *Gp;
  float *zstate, *out;
  int s0, s1, do_enc, do_epi;
};

__global__ __launch_bounds__(256, 1) void scan_kernel(ScanP p){
  const int tid = threadIdx.x;
  const int b = blockIdx.x;
  const int lane = tid & 63, wid = tid >> 6;
  __shared__ __align__(16) u32 Gs[128*128];   // 64KB, [kp][h] packed pairs
  __shared__ __align__(16) u32 zp[64];        // z as half2 pairs
  __shared__ __align__(16) u32 a1p[128];
  __shared__ __align__(16) u32 a2p[128];
  __shared__ __align__(16) float dr[HID2];
  __shared__ __align__(16) float zf[HID];
  __shared__ __align__(16) float sc1[HID2];
  __shared__ float red[8];

  // ---- persistent packed-half weight registers (192 VGPRs) ----
  u32 w1p[64];
  #pragma unroll
  for (int j = 0; j < 64; ++j)
    w1p[j] = pkh2(p.vW1[(size_t)(2*j)*HID2 + tid], p.vW1[(size_t)(2*j+1)*HID2 + tid]);
  u32 w2p[128];
  #pragma unroll
  for (int j = 0; j < 128; ++j)
    w2p[j] = pkh2(p.vW2[(size_t)(2*j)*HID2 + tid], p.vW2[(size_t)(2*j+1)*HID2 + tid]);

  float mu, sq;
  if (p.do_enc){
    if (tid < IND) sc1[tid] = p.path[(b*SS + 0)*IND + tid];
    __syncthreads();
    float acc = 0.f;
    if (tid < HID){
      acc = p.eb1[tid];
      #pragma unroll 8
      for (int i = 0; i < IND; ++i) acc = fmaf(sc1[i], p.eW1[i*HID + tid], acc);
    }
    float cx = (tid < HID) ? acc : 0.f;
    bsum2(cx, cx*cx, red, tid, mu, sq);
    mu *= (1.f/HID); float var = sq*(1.f/HID) - mu*mu; float rstd = rsqrtf(var + 1e-5f);
    if (tid < HID) dr[tid] = gelu_f((acc - mu)*rstd*p.eg1[tid] + p.ebt1[tid]);
    __syncthreads();
    float acc2 = 0.f;
    if (tid < HID){
      acc2 = p.eb2[tid];
      #pragma unroll 8
      for (int h = 0; h < HID; ++h) acc2 = fmaf(dr[h], p.eW2[h*HID + tid], acc2);
    }
    cx = (tid < HID) ? acc2 : 0.f;
    bsum2(cx, cx*cx, red, tid, mu, sq);
    mu *= (1.f/HID); float var2 = sq*(1.f/HID) - mu*mu; float rstd2 = rsqrtf(var2 + 1e-5f);
    if (tid < HID) zf[tid] = (acc2 - mu)*rstd2*p.eg2[tid] + p.ebt2[tid];
    __syncthreads();
  } else {
    if (tid < HID) zf[tid] = p.zstate[b*HID + tid];
    __syncthreads();
  }
  float zc = (tid < HID) ? zf[tid] : 0.f;

  const float rb1 = p.b1[tid], rg1 = p.g1[tid], rbt1 = p.bt1[tid];
  const float rb2 = p.b2[tid], rg2 = p.g2[tid], rbt2 = p.bt2[tid];
  const int h3 = tid & 127, hf = tid >> 7;

  for (int s = p.s0; s < p.s1; ++s){
    const float hbv = p.hb[b*NSTEP + s];
    const float gbv = (tid < HID) ? p.gb[(b*NSTEP + s)*HID + tid] : 0.f;
    // ---- stage this step's G into LDS (reused by 4 stages) ----
    const uint4* gsrc = (const uint4*)(p.Gp + ((size_t)(s - p.s0)*BB + b)*16384);
    uint4* Gs4 = (uint4*)Gs;
    #pragma unroll
    for (int i = 0; i < 16; ++i) Gs4[tid + 256*i] = gsrc[tid + 256*i];
    if (tid < HID) ((u16*)zp)[tid] = f2h(zc);
    float ksum = 0.f;
    __syncthreads();                                // publish Gs + zp

    #pragma unroll 1
    for (int st = 0; st < 4; ++st){
      // ---- layer1: K=128 (64 dot2), weights in regs ----
      float e0 = 0.f, e1 = 0.f, e2 = 0.f, e3 = 0.f;
      const uint4* zp4 = (const uint4*)zp;
      #pragma unroll
      for (int j = 0; j < 16; ++j){
        uint4 zq = zp4[j];
        e0 = dot2f(zq.x, w1p[4*j+0], e0);
        e1 = dot2f(zq.y, w1p[4*j+1], e1);
        e2 = dot2f(zq.z, w1p[4*j+2], e2);
        e3 = dot2f(zq.w, w1p[4*j+3], e3);
      }
      float acc = rb1 + ((e0 + e1) + (e2 + e3));
      float sx = acc, sy = acc*acc;
      #pragma unroll
      for (int o = 32; o >= 1; o >>= 1){ sx += __shfl_xor(sx, o); sy += __shfl_xor(sy, o); }
      if (lane == 0){ red[wid*2] = sx; red[wid*2+1] = sy; }
      __syncthreads();
      float m1 = (red[0]+red[2]+red[4]+red[6])*(1.f/HID2);
      float q1 = (red[1]+red[3]+red[5]+red[7])*(1.f/HID2);
      float rs1 = rsqrtf(q1 - m1*m1 + 1e-5f);
      ((u16*)a1p)[tid] = f2h(gelu_f((acc - m1)*rs1*rg1 + rbt1));
      __syncthreads();                              // publish a1p (also protects red)
      // ---- layer2: K=256 (128 dot2), weights in regs ----
      float f0 = 0.f, f1 = 0.f, f2 = 0.f, f3 = 0.f;
      const uint4* a1p4 = (const uint4*)a1p;
      #pragma unroll
      for (int j = 0; j < 32; ++j){
        uint4 aq = a1p4[j];
        f0 = dot2f(aq.x, w2p[4*j+0], f0);
        f1 = dot2f(aq.y, w2p[4*j+1], f1);
        f2 = dot2f(aq.z, w2p[4*j+2], f2);
        f3 = dot2f(aq.w, w2p[4*j+3], f3);
      }
      float acc2 = rb2 + ((f0 + f1) + (f2 + f3));
      sx = acc2; sy = acc2*acc2;
      #pragma unroll
      for (int o = 32; o >= 1; o >>= 1){ sx += __shfl_xor(sx, o); sy += __shfl_xor(sy, o); }
      if (lane == 0){ red[wid*2] = sx; red[wid*2+1] = sy; }
      __syncthreads();
      float m2 = (red[0]+red[2]+red[4]+red[6])*(1.f/HID2);
      float q2 = (red[1]+red[3]+red[5]+red[7])*(1.f/HID2);
      float rs2 = rsqrtf(q2 - m2*m2 + 1e-5f);
      ((u16*)a2p)[tid] = f2h(gelu_f((acc2 - m2)*rs2*rg2 + rbt2));
      __syncthreads();                              // publish a2p
      // ---- layer3: drift halves from LDS-resident G ----
      float d0 = 0.f, d1 = 0.f, d2 = 0.f, d3 = 0.f;
      const uint4* a2p4 = (const uint4*)a2p;
      const u32* gcol = Gs + (hf << 13) + h3;       // hf*64 rows of 128 u32
      #pragma unroll
      for (int j = 0; j < 16; ++j){
        uint4 aq = a2p4[hf*16 + j];
        d0 = dot2f(aq.x, gcol[(4*j+0)*128], d0);
        d1 = dot2f(aq.y, gcol[(4*j+1)*128], d1);
        d2 = dot2f(aq.z, gcol[(4*j+2)*128], d2);
        d3 = dot2f(aq.w, gcol[(4*j+3)*128], d3);
      }
      dr[tid] = (d0 + d1) + (d2 + d3);
      __syncthreads();                              // publish dr
      if (tid < HID){
        float kv = dr[tid] + dr[tid + HID] + gbv;
        ksum += ((st == 0 || st == 3) ? 1.f : 2.f)*kv;
        if (st < 3){
          float zs = zc + ((st == 2) ? hbv : 0.5f*hbv)*kv;
          ((u16*)zp)[tid] = f2h(zs);
        }
      }
      __syncthreads();                              // publish zp
    }
    if (tid < HID) zc += hbv*(1.f/6.f)*ksum;
  }

  if (p.do_epi){
    if (tid < HID) zf[tid] = zc;
    __syncthreads();
    if (tid < HID){
      float v = p.bv[tid];
      #pragma unroll 8
      for (int h = 0; h < HID; ++h) v = fmaf(zf[h], p.Wv[h*HID + tid], v);
      sc1[tid] = v;
    }
    __syncthreads();
    if (tid < HID){
      float f = p.bo[tid];
      #pragma unroll 8
      for (int h = 0; h < HID; ++h) f = fmaf(sc1[h], p.Wo[h*HID + tid], f);
      dr[tid] = f;
    }
    __syncthreads();
    if (tid < HID){
      float hd = p.db1[tid];
      #pragma unroll 8
      for (int h = 0; h < HID; ++h) hd = fmaf(dr[h], p.dW1[h*HID + tid], hd);
      sc1[tid] = gelu_f(hd);
    }
    __syncthreads();
    if (tid < 10){
      float t = p.db2[tid];
      #pragma unroll 8
      for (int h = 0; h < HID; ++h) t = fmaf(sc1[h], p.dW2[h*10 + tid], t);
      p.out[b*10 + tid] = t;
    }
    if (tid == 0) p.out[BB*10 + b] = 1.0f;          // softmax over singleton axis == 1
  } else {
    if (tid < HID) p.zstate[b*HID + tid] = zc;
  }
}

extern "C" void kernel_launch(void* const* d_in, const int* in_sizes, int n_in,
                              void* d_out, int out_size, void* d_ws, size_t ws_size,
                              hipStream_t stream){
  const float* path  = (const float*)d_in[0];
  const float* ts    = (const float*)d_in[1];
  const float* eW1   = (const float*)d_in[2];
  const float* eb1   = (const float*)d_in[3];
  const float* eg1   = (const float*)d_in[4];
  const float* ebt1  = (const float*)d_in[5];
  const float* eW2   = (const float*)d_in[6];
  const float* eb2   = (const float*)d_in[7];
  const float* eg2   = (const float*)d_in[8];
  const float* ebt2  = (const float*)d_in[9];
  const float* vW1   = (const float*)d_in[10];
  const float* vb1   = (const float*)d_in[11];
  const float* vg1   = (const float*)d_in[12];
  const float* vbt1  = (const float*)d_in[13];
  const float* vW2   = (const float*)d_in[14];
  const float* vb2   = (const float*)d_in[15];
  const float* vg2   = (const float*)d_in[16];
  const float* vbt2  = (const float*)d_in[17];
  const float* vW3   = (const float*)d_in[18];
  const float* vb3   = (const float*)d_in[19];
  const float* Wv    = (const float*)d_in[24];
  const float* bv    = (const float*)d_in[25];
  const float* Wo    = (const float*)d_in[26];
  const float* bo    = (const float*)d_in[27];
  const float* dW1   = (const float*)d_in[28];
  const float* db1   = (const float*)d_in[29];
  const float* dW2   = (const float*)d_in[30];
  const float* db2   = (const float*)d_in[31];

  char* wsb = (char*)d_ws;
  float* z_state = (float*)(wsb + 0);              // 64 KB
  u32*   dxh = (u32*)(wsb + 65536);                // 248 KB
  float* hb  = (float*)(wsb + 319488);             // 15.5 KB
  float* gb  = (float*)(wsb + 344064);             // 1.94 MB
  u32*   w3h = (u32*)(wsb + 2375680);              // 2 MB
  u32*   Gp  = (u32*)(wsb + 4472832);              // up to 248 MB

  hipLaunchKernelGGL(prep_misc, dim3(BB), dim3(128), 0, stream, path, ts, vb3, dxh, hb, gb);
  hipLaunchKernelGGL(pack_w3, dim3(2048), dim3(256), 0, stream, vW3, w3h);

  const size_t per_step = (size_t)BB * 16384 * 4;  // 8 MB per step
  size_t gav = (ws_size > 4472832) ? (ws_size - 4472832) : per_step;
  int chunk = (int)(gav / per_step);
  if (chunk < 1) chunk = 1;
  if (chunk > NSTEP) chunk = NSTEP;

  for (int s0 = 0; s0 < NSTEP; s0 += chunk){
    int cs = (NSTEP - s0 < chunk) ? (NSTEP - s0) : chunk;
    hipLaunchKernelGGL(gprep_h, dim3(64, cs), dim3(256), 0, stream, w3h, dxh, Gp, s0);
    ScanP P;
    P.path = path;
    P.eW1 = eW1; P.eb1 = eb1; P.eg1 = eg1; P.ebt1 = ebt1;
    P.eW2 = eW2; P.eb2 = eb2; P.eg2 = eg2; P.ebt2 = ebt2;
    P.vW1 = vW1; P.b1 = vb1; P.g1 = vg1; P.bt1 = vbt1;
    P.vW2 = vW2; P.b2 = vb2; P.g2 = vg2; P.bt2 = vbt2;
    P.Wv = Wv; P.bv = bv; P.Wo = Wo; P.bo = bo;
    P.dW1 = dW1; P.db1 = db1; P.dW2 = dW2; P.db2 = db2;
    P.hb = hb; P.gb = gb; P.Gp = Gp;
    P.zstate = z_state; P.out = (float*)d_out;
    P.s0 = s0; P.s1 = s0 + cs;
    P.do_enc = (s0 == 0) ? 1 : 0;
    P.do_epi = (s0 + cs == NSTEP) ? 1 : 0;
    hipLaunchKernelGGL(scan_kernel, dim3(BB), dim3(256), 0, stream, P);
  }
}

// Round 5
// 895.855 us; speedup vs baseline: 1.5923x; 1.0028x over previous
//
#include <hip/hip_runtime.h>
#include <hip/hip_bf16.h>

#define BB 128
#define SS 32
#define NSTEP 31
#define IND 32
#define HID 128
#define HID2 256

typedef unsigned short u16;
typedef unsigned int u32;
typedef _Float16 f16;
typedef f16 h2 __attribute__((ext_vector_type(2)));
typedef __fp16 fp16v2 __attribute__((ext_vector_type(2)));

__device__ __forceinline__ float dot2f(u32 a, u32 b, float c){
#if __has_builtin(__builtin_amdgcn_fdot2)
  h2 ha, hb; __builtin_memcpy(&ha, &a, 4); __builtin_memcpy(&hb, &b, 4);
  return __builtin_amdgcn_fdot2(ha, hb, c, false);
#else
  h2 ha, hb; __builtin_memcpy(&ha, &a, 4); __builtin_memcpy(&hb, &b, 4);
  return c + (float)ha[0]*(float)hb[0] + (float)ha[1]*(float)hb[1];
#endif
}
__device__ __forceinline__ u32 h2add(u32 a, u32 b){
  h2 x, y; __builtin_memcpy(&x, &a, 4); __builtin_memcpy(&y, &b, 4);
  h2 r = x + y; u32 u; __builtin_memcpy(&u, &r, 4); return u;
}
__device__ __forceinline__ u32 pkh2(float a, float b){
  fp16v2 r = __builtin_amdgcn_cvt_pkrtz(a, b);
  u32 u; __builtin_memcpy(&u, &r, 4); return u;
}
__device__ __forceinline__ u16 f2h(float f){ f16 h = (f16)f; u16 u; __builtin_memcpy(&u, &h, 2); return u; }
__device__ __forceinline__ float h2f(u16 u){ f16 h; __builtin_memcpy(&h, &u, 2); return (float)h; }
__device__ __forceinline__ float gelu_f(float x){ return 0.5f * x * (1.0f + erff(x * 0.70710678118654752440f)); }

// ---- DPP wave64 sum: result valid in lane 63; identity-add formulation (old=0) ----
__device__ __forceinline__ float wred_step(float v, int ctrl, int rmask){
  int t = __builtin_amdgcn_update_dpp(0, __builtin_amdgcn_readfirstlane(0) /*dummy*/ , 0, 0, 0, false);
  (void)t; return v; // never used; kept out — see wred below
}
__device__ __forceinline__ float wred(float v){
  int iv; float tf;
  #define DPPADD(CTRL, RMASK) \
    __builtin_memcpy(&iv, &v, 4); \
    iv = __builtin_amdgcn_update_dpp(0, iv, CTRL, RMASK, 0xf, true); \
    __builtin_memcpy(&tf, &iv, 4); \
    v += tf;
  DPPADD(0x111, 0xf)   // row_shr:1
  DPPADD(0x112, 0xf)   // row_shr:2
  DPPADD(0x114, 0xf)   // row_shr:4
  DPPADD(0x118, 0xf)   // row_shr:8  -> lane15 of each row16 = row sum
  DPPADD(0x142, 0xa)   // row_bcast15 into rows 1,3
  DPPADD(0x143, 0xc)   // row_bcast31 into rows 2,3 -> lane63 = wave sum
  #undef DPPADD
  return v;
}
__device__ __forceinline__ float bcast63(float v){
  int iv; __builtin_memcpy(&iv, &v, 4);
  int r = __builtin_amdgcn_readlane(iv, 63);
  float f; __builtin_memcpy(&f, &r, 4); return f;
}

// block-wide sum of (x,y) over 256 threads — used in enc/epi only
__device__ __forceinline__ void bsum2(float x, float y, float* red, int tid, float& ox, float& oy){
  #pragma unroll
  for (int off = 32; off >= 1; off >>= 1){ x += __shfl_xor(x, off); y += __shfl_xor(y, off); }
  __syncthreads();
  if ((tid & 63) == 0){ red[(tid >> 6)*2] = x; red[(tid >> 6)*2 + 1] = y; }
  __syncthreads();
  ox = red[0] + red[2] + red[4] + red[6];
  oy = red[1] + red[3] + red[5] + red[7];
}

// ---------------- prep: dxh (packed half2 dX), hb, gb ----------------
__global__ __launch_bounds__(128) void prep_misc(const float* __restrict__ path,
                                                 const float* __restrict__ ts,
                                                 const float* __restrict__ b3,
                                                 u32* __restrict__ dxh,
                                                 float* __restrict__ hb,
                                                 float* __restrict__ gb){
  const int b = blockIdx.x, tid = threadIdx.x;
  __shared__ float sdx[NSTEP * IND];
  for (int t = tid; t < NSTEP * IND; t += 128){
    int s = t >> 5, i = t & 31;
    float dt = ts[b*SS + s + 1] - ts[b*SS + s];
    sdx[t] = (path[(b*SS + s + 1)*IND + i] - path[(b*SS + s)*IND + i]) / dt;
  }
  if (tid < NSTEP) hb[b*NSTEP + tid] = ts[b*SS + tid + 1] - ts[b*SS + tid];
  __syncthreads();
  for (int t = tid; t < NSTEP * 16; t += 128){
    int s = t >> 4, i2 = t & 15;
    dxh[((size_t)b*NSTEP + s)*16 + i2] = pkh2(sdx[s*IND + 2*i2], sdx[s*IND + 2*i2 + 1]);
  }
  if (tid < HID){
    float w[IND];
    #pragma unroll
    for (int i = 0; i < IND; ++i) w[i] = b3[tid*IND + i];
    for (int s = 0; s < NSTEP; ++s){
      float a = 0.f;
      #pragma unroll
      for (int i = 0; i < IND; ++i) a = fmaf(w[i], sdx[s*IND + i], a);
      gb[(b*NSTEP + s)*HID + tid] = a;
    }
  }
}

// ---------------- pack vf_W3 (fp32) -> half2 pairs over the i-dimension ----------------
__global__ __launch_bounds__(256) void pack_w3(const float* __restrict__ W3, u32* __restrict__ w3h){
  int i = blockIdx.x*256 + threadIdx.x;
  if (i < (HID2*HID*IND)/2) w3h[i] = pkh2(W3[2*i], W3[2*i + 1]);
}

// ---------------- G pair-packed: Gp[(sl*BB+b)*16384 + kp*128 + h] ----------------
__global__ __launch_bounds__(256) void gprep_h(const u32* __restrict__ w3h,
                                               const u32* __restrict__ dxh,
                                               u32* __restrict__ Gp, int s0){
  const int tid = threadIdx.x;
  const int sl = blockIdx.y; const int s = s0 + sl;
  const int lin = blockIdx.x*256 + tid;
  const int kp = lin >> 7, h = lin & 127;
  const uint4* wa = (const uint4*)(w3h + ((size_t)(2*kp)*HID + h)*16);
  const uint4* wb = (const uint4*)(w3h + ((size_t)(2*kp+1)*HID + h)*16);
  uint4 A0 = wa[0], A1 = wa[1], A2 = wa[2], A3 = wa[3];
  uint4 B0 = wb[0], B1 = wb[1], B2 = wb[2], B3 = wb[3];
  __shared__ u32 sdx[BB * 16];
  for (int t = tid; t < BB * 16; t += 256){
    int bb = t >> 4, i2 = t & 15;
    sdx[t] = dxh[((size_t)bb*NSTEP + s)*16 + i2];
  }
  __syncthreads();
  const size_t outbase = (size_t)sl * BB * 16384 + lin;
  for (int bb = 0; bb < BB; ++bb){
    const uint4* dp = (const uint4*)&sdx[bb*16];
    uint4 D0 = dp[0], D1 = dp[1], D2 = dp[2], D3 = dp[3];
    float g0 = 0.f, g1 = 0.f, g2 = 0.f, g3 = 0.f;
    g0 = dot2f(D0.x, A0.x, g0); g0 = dot2f(D0.y, A0.y, g0);
    g0 = dot2f(D0.z, A0.z, g0); g0 = dot2f(D0.w, A0.w, g0);
    g2 = dot2f(D1.x, A1.x, g2); g2 = dot2f(D1.y, A1.y, g2);
    g2 = dot2f(D1.z, A1.z, g2); g2 = dot2f(D1.w, A1.w, g2);
    g0 = dot2f(D2.x, A2.x, g0); g0 = dot2f(D2.y, A2.y, g0);
    g0 = dot2f(D2.z, A2.z, g0); g0 = dot2f(D2.w, A2.w, g0);
    g2 = dot2f(D3.x, A3.x, g2); g2 = dot2f(D3.y, A3.y, g2);
    g2 = dot2f(D3.z, A3.z, g2); g2 = dot2f(D3.w, A3.w, g2);
    g1 = dot2f(D0.x, B0.x, g1); g1 = dot2f(D0.y, B0.y, g1);
    g1 = dot2f(D0.z, B0.z, g1); g1 = dot2f(D0.w, B0.w, g1);
    g3 = dot2f(D1.x, B1.x, g3); g3 = dot2f(D1.y, B1.y, g3);
    g3 = dot2f(D1.z, B1.z, g3); g3 = dot2f(D1.w, B1.w, g3);
    g1 = dot2f(D2.x, B2.x, g1); g1 = dot2f(D2.y, B2.y, g1);
    g1 = dot2f(D2.z, B2.z, g1); g1 = dot2f(D2.w, B2.w, g1);
    g3 = dot2f(D3.x, B3.x, g3); g3 = dot2f(D3.y, B3.y, g3);
    g3 = dot2f(D3.z, B3.z, g3); g3 = dot2f(D3.w, B3.w, g3);
    Gp[outbase + (size_t)bb*16384] = pkh2(g0 + g2, g1 + g3);
  }
}

// ---------------- sequential RK4 scan: one block per batch element ----------------
struct ScanP {
  const float *path;
  const float *eW1,*eb1,*eg1,*ebt1,*eW2,*eb2,*eg2,*ebt2;
  const float *vW1,*b1,*g1,*bt1;
  const float *vW2,*b2,*g2,*bt2;
  const float *Wv,*bv,*Wo,*bo,*dW1,*db1,*dW2,*db2;
  const float *hb,*gb;
  const u32 *Gp;
  float *zstate, *out;
  int s0, s1, do_enc, do_epi;
};

__global__ __launch_bounds__(256, 1) void scan_kernel(ScanP p){
  const int tid = threadIdx.x;
  const int b = blockIdx.x;
  const int lane = tid & 63, wid = tid >> 6;
  __shared__ __align__(16) u32 Gs[128*128];    // 64KB [kp][h]
  __shared__ __align__(16) u16 zcp_h[HID];     // zc packed fp16 (per step)
  __shared__ __align__(16) u16 gbp_h[HID];     // gb packed fp16 (per step)
  __shared__ __align__(16) u16 a1p_h[HID2];
  __shared__ __align__(16) u16 a2p_h[HID2];
  __shared__ __align__(16) u16 dlo_h[HID];     // drift low-half  (k 0..127 of a2)
  __shared__ __align__(16) u16 dhi_h[HID];     // drift high-half
  __shared__ __align__(16) float zf[HID];
  __shared__ __align__(16) float sc1[HID2];
  __shared__ __align__(16) float red[8];

  // ---- persistent packed-half weight registers (192 VGPRs) ----
  u32 w1p[64];
  #pragma unroll
  for (int j = 0; j < 64; ++j)
    w1p[j] = pkh2(p.vW1[(size_t)(2*j)*HID2 + tid], p.vW1[(size_t)(2*j+1)*HID2 + tid]);
  u32 w2p[128];
  #pragma unroll
  for (int j = 0; j < 128; ++j)
    w2p[j] = pkh2(p.vW2[(size_t)(2*j)*HID2 + tid], p.vW2[(size_t)(2*j+1)*HID2 + tid]);

  float mu, sq;
  if (p.do_enc){
    if (tid < IND) sc1[tid] = p.path[(b*SS + 0)*IND + tid];
    __syncthreads();
    float acc = 0.f;
    if (tid < HID){
      acc = p.eb1[tid];
      #pragma unroll 8
      for (int i = 0; i < IND; ++i) acc = fmaf(sc1[i], p.eW1[i*HID + tid], acc);
    }
    float cx = (tid < HID) ? acc : 0.f;
    bsum2(cx, cx*cx, red, tid, mu, sq);
    mu *= (1.f/HID); float var = sq*(1.f/HID) - mu*mu; float rstd = rsqrtf(var + 1e-5f);
    if (tid < HID) zf[tid] = gelu_f((acc - mu)*rstd*p.eg1[tid] + p.ebt1[tid]);
    __syncthreads();
    float acc2 = 0.f;
    if (tid < HID){
      acc2 = p.eb2[tid];
      #pragma unroll 8
      for (int h = 0; h < HID; ++h) acc2 = fmaf(zf[h], p.eW2[h*HID + tid], acc2);
    }
    cx = (tid < HID) ? acc2 : 0.f;
    bsum2(cx, cx*cx, red, tid, mu, sq);
    mu *= (1.f/HID); float var2 = sq*(1.f/HID) - mu*mu; float rstd2 = rsqrtf(var2 + 1e-5f);
    __syncthreads();   // zf readers done before overwrite
    if (tid < HID) zf[tid] = (acc2 - mu)*rstd2*p.eg2[tid] + p.ebt2[tid];
    __syncthreads();
  } else {
    if (tid < HID) zf[tid] = p.zstate[b*HID + tid];
    __syncthreads();
  }
  float zc = (tid < HID) ? zf[tid] : 0.f;

  const float rb1 = p.b1[tid], rg1 = p.g1[tid], rbt1 = p.bt1[tid];
  const float rb2 = p.b2[tid], rg2 = p.g2[tid], rbt2 = p.bt2[tid];
  const int h3 = tid & 127, hf = tid >> 7;

  for (int s = p.s0; s < p.s1; ++s){
    const float hbv = p.hb[b*NSTEP + s];
    const float gbv = (tid < HID) ? p.gb[(b*NSTEP + s)*HID + tid] : 0.f;
    // ---- stage this step's G into LDS; publish zc & gb as fp16 ----
    const uint4* gsrc = (const uint4*)(p.Gp + ((size_t)(s - p.s0)*BB + b)*16384);
    uint4* Gs4 = (uint4*)Gs;
    #pragma unroll
    for (int i = 0; i < 16; ++i) Gs4[tid + 256*i] = gsrc[tid + 256*i];
    if (tid < HID){ zcp_h[tid] = f2h(zc); gbp_h[tid] = f2h(gbv); }
    float ksum = 0.f;
    __syncthreads();

    // ---- per-step layer1 constants: Szc = z.W1col, Sgb = gb.W1col ----
    float sz0 = 0.f, sz1 = 0.f, sg0 = 0.f, sg1 = 0.f;
    {
      const uint4* zp4 = (const uint4*)zcp_h;   // 16 uint4
      const uint4* gp4 = (const uint4*)gbp_h;
      #pragma unroll
      for (int j = 0; j < 16; ++j){
        uint4 zq = zp4[j], gq = gp4[j];
        sz0 = dot2f(zq.x, w1p[4*j+0], sz0); sz1 = dot2f(zq.y, w1p[4*j+1], sz1);
        sz0 = dot2f(zq.z, w1p[4*j+2], sz0); sz1 = dot2f(zq.w, w1p[4*j+3], sz1);
        sg0 = dot2f(gq.x, w1p[4*j+0], sg0); sg1 = dot2f(gq.y, w1p[4*j+1], sg1);
        sg0 = dot2f(gq.z, w1p[4*j+2], sg0); sg1 = dot2f(gq.w, w1p[4*j+3], sg1);
      }
    }
    const float Szc = sz0 + sz1, Sgb = sg0 + sg1;

    #pragma unroll 1
    for (int st = 0; st < 4; ++st){
      // ---- layer1: acc = rb1 + Szc + c*(Sdr + Sgb) ----
      float acc;
      if (st == 0){
        acc = rb1 + Szc;
      } else {
        const float c = (st == 3) ? hbv : 0.5f*hbv;
        float e0 = 0.f, e1 = 0.f, e2 = 0.f, e3 = 0.f;
        const uint4* lo4 = (const uint4*)dlo_h;  // 16 uint4
        const uint4* hi4 = (const uint4*)dhi_h;
        #pragma unroll
        for (int j = 0; j < 16; ++j){
          uint4 lo = lo4[j], hi = hi4[j];
          e0 = dot2f(h2add(lo.x, hi.x), w1p[4*j+0], e0);
          e1 = dot2f(h2add(lo.y, hi.y), w1p[4*j+1], e1);
          e2 = dot2f(h2add(lo.z, hi.z), w1p[4*j+2], e2);
          e3 = dot2f(h2add(lo.w, hi.w), w1p[4*j+3], e3);
        }
        acc = rb1 + Szc + c*(((e0 + e1) + (e2 + e3)) + Sgb);
      }
      float s1 = wred(acc), s2 = wred(acc*acc);
      if (lane == 63){ red[wid*2] = s1; red[wid*2+1] = s2; }
      __syncthreads();                                   // b1
      {
        const float4* r4 = (const float4*)red;
        float4 ra = r4[0], rb = r4[1];
        float m1 = (ra.x + ra.z + rb.x + rb.z)*(1.f/HID2);
        float q1 = (ra.y + ra.w + rb.y + rb.w)*(1.f/HID2);
        float rs1 = rsqrtf(q1 - m1*m1 + 1e-5f);
        a1p_h[tid] = f2h(gelu_f((acc - m1)*rs1*rg1 + rbt1));
      }
      __syncthreads();                                   // b2
      // ---- layer2: K=256 ----
      float f0 = 0.f, f1 = 0.f, f2 = 0.f, f3 = 0.f;
      const uint4* a1p4 = (const uint4*)a1p_h;           // 32 uint4
      #pragma unroll
      for (int j = 0; j < 32; ++j){
        uint4 aq = a1p4[j];
        f0 = dot2f(aq.x, w2p[4*j+0], f0);
        f1 = dot2f(aq.y, w2p[4*j+1], f1);
        f2 = dot2f(aq.z, w2p[4*j+2], f2);
        f3 = dot2f(aq.w, w2p[4*j+3], f3);
      }
      float acc2 = rb2 + ((f0 + f1) + (f2 + f3));
      s1 = wred(acc2); s2 = wred(acc2*acc2);
      if (lane == 63){ red[wid*2] = s1; red[wid*2+1] = s2; }
      __syncthreads();                                   // b3
      {
        const float4* r4 = (const float4*)red;
        float4 ra = r4[0], rb = r4[1];
        float m2 = (ra.x + ra.z + rb.x + rb.z)*(1.f/HID2);
        float q2 = (ra.y + ra.w + rb.y + rb.w)*(1.f/HID2);
        float rs2 = rsqrtf(q2 - m2*m2 + 1e-5f);
        a2p_h[tid] = f2h(gelu_f((acc2 - m2)*rs2*rg2 + rbt2));
      }
      __syncthreads();                                   // b4
      // ---- layer3: drift half from LDS G ----
      float d0 = 0.f, d1 = 0.f, d2 = 0.f, d3 = 0.f;
      const uint4* a2p4 = (const uint4*)a2p_h;
      const u32* gcol = Gs + (hf << 13) + h3;
      #pragma unroll
      for (int j = 0; j < 16; ++j){
        uint4 aq = a2p4[hf*16 + j];
        d0 = dot2f(aq.x, gcol[(4*j+0)*128], d0);
        d1 = dot2f(aq.y, gcol[(4*j+1)*128], d1);
        d2 = dot2f(aq.z, gcol[(4*j+2)*128], d2);
        d3 = dot2f(aq.w, gcol[(4*j+3)*128], d3);
      }
      float dsum = (d0 + d1) + (d2 + d3);
      if (hf == 0) dlo_h[h3] = f2h(dsum); else dhi_h[h3] = f2h(dsum);
      __syncthreads();                                   // b5
      if (tid < HID){
        float kv = h2f(dlo_h[tid]) + h2f(dhi_h[tid]) + gbv;
        ksum += ((st == 0 || st == 3) ? 1.f : 2.f)*kv;
      }
    }
    if (tid < HID) zc += hbv*(1.f/6.f)*ksum;
  }

  if (p.do_epi){
    if (tid < HID) zf[tid] = zc;
    __syncthreads();
    if (tid < HID){
      float v = p.bv[tid];
      #pragma unroll 8
      for (int h = 0; h < HID; ++h) v = fmaf(zf[h], p.Wv[h*HID + tid], v);
      sc1[tid] = v;
    }
    __syncthreads();
    if (tid < HID){
      float f = p.bo[tid];
      #pragma unroll 8
      for (int h = 0; h < HID; ++h) f = fmaf(sc1[h], p.Wo[h*HID + tid], f);
      sc1[HID + tid] = f;
    }
    __syncthreads();
    if (tid < HID){
      float hd = p.db1[tid];
      #pragma unroll 8
      for (int h = 0; h < HID; ++h) hd = fmaf(sc1[HID + h], p.dW1[h*HID + tid], hd);
      zf[tid] = gelu_f(hd);
    }
    __syncthreads();
    if (tid < 10){
      float t = p.db2[tid];
      #pragma unroll 8
      for (int h = 0; h < HID; ++h) t = fmaf(zf[h], p.dW2[h*10 + tid], t);
      p.out[b*10 + tid] = t;
    }
    if (tid == 0) p.out[BB*10 + b] = 1.0f;   // softmax over singleton axis == 1
  } else {
    if (tid < HID) p.zstate[b*HID + tid] = zc;
  }
}

extern "C" void kernel_launch(void* const* d_in, const int* in_sizes, int n_in,
                              void* d_out, int out_size, void* d_ws, size_t ws_size,
                              hipStream_t stream){
  const float* path  = (const float*)d_in[0];
  const float* ts    = (const float*)d_in[1];
  const float* eW1   = (const float*)d_in[2];
  const float* eb1   = (const float*)d_in[3];
  const float* eg1   = (const float*)d_in[4];
  const float* ebt1  = (const float*)d_in[5];
  const float* eW2   = (const float*)d_in[6];
  const float* eb2   = (const float*)d_in[7];
  const float* eg2   = (const float*)d_in[8];
  const float* ebt2  = (const float*)d_in[9];
  const float* vW1   = (const float*)d_in[10];
  const float* vb1   = (const float*)d_in[11];
  const float* vg1   = (const float*)d_in[12];
  const float* vbt1  = (const float*)d_in[13];
  const float* vW2   = (const float*)d_in[14];
  const float* vb2   = (const float*)d_in[15];
  const float* vg2   = (const float*)d_in[16];
  const float* vbt2  = (const float*)d_in[17];
  const float* vW3   = (const float*)d_in[18];
  const float* vb3   = (const float*)d_in[19];
  const float* Wv    = (const float*)d_in[24];
  const float* bv    = (const float*)d_in[25];
  const float* Wo    = (const float*)d_in[26];
  const float* bo    = (const float*)d_in[27];
  const float* dW1   = (const float*)d_in[28];
  const float* db1   = (const float*)d_in[29];
  const float* dW2   = (const float*)d_in[30];
  const float* db2   = (const float*)d_in[31];

  char* wsb = (char*)d_ws;
  float* z_state = (float*)(wsb + 0);              // 64 KB
  u32*   dxh = (u32*)(wsb + 65536);                // 248 KB
  float* hb  = (float*)(wsb + 319488);             // 15.5 KB
  float* gb  = (float*)(wsb + 344064);             // 1.94 MB
  u32*   w3h = (u32*)(wsb + 2375680);              // 2 MB
  u32*   Gp  = (u32*)(wsb + 4472832);              // up to 248 MB

  hipLaunchKernelGGL(prep_misc, dim3(BB), dim3(128), 0, stream, path, ts, vb3, dxh, hb, gb);
  hipLaunchKernelGGL(pack_w3, dim3(2048), dim3(256), 0, stream, vW3, w3h);

  const size_t per_step = (size_t)BB * 16384 * 4;  // 8 MB per step
  size_t gav = (ws_size > 4472832) ? (ws_size - 4472832) : per_step;
  int chunk = (int)(gav / per_step);
  if (chunk < 1) chunk = 1;
  if (chunk > NSTEP) chunk = NSTEP;

  for (int s0 = 0; s0 < NSTEP; s0 += chunk){
    int cs = (NSTEP - s0 < chunk) ? (NSTEP - s0) : chunk;
    hipLaunchKernelGGL(gprep_h, dim3(64, cs), dim3(256), 0, stream, w3h, dxh, Gp, s0);
    ScanP P;
    P.path = path;
    P.eW1 = eW1; P.eb1 = eb1; P.eg1 = eg1; P.ebt1 = ebt1;
    P.eW2 = eW2; P.eb2 = eb2; P.eg2 = eg2; P.ebt2 = ebt2;
    P.vW1 = vW1; P.b1 = vb1; P.g1 = vg1; P.bt1 = vbt1;
    P.vW2 = vW2; P.b2 = vb2; P.g2 = vg2; P.bt2 = vbt2;
    P.Wv = Wv; P.bv = bv; P.Wo = Wo; P.bo = bo;
    P.dW1 = dW1; P.db1 = db1; P.dW2 = dW2; P.db2 = db2;
    P.hb = hb; P.gb = gb; P.Gp = Gp;
    P.zstate = z_state; P.out = (float*)d_out;
    P.s0 = s0; P.s1 = s0 + cs;
    P.do_enc = (s0 == 0) ? 1 : 0;
    P.do_epi = (s0 + cs == NSTEP) ? 1 : 0;
    hipLaunchKernelGGL(scan_kernel, dim3(BB), dim3(256), 0, stream, P);
  }
}

// Round 6
// 608.604 us; speedup vs baseline: 2.3439x; 1.4720x over previous
//
#include <hip/hip_runtime.h>
#include <hip/hip_bf16.h>

#define BB 128
#define SS 32
#define NSTEP 31
#define IND 32
#define HID 128
#define HID2 256

typedef unsigned short u16;
typedef unsigned int u32;
typedef _Float16 f16;
typedef f16 h2 __attribute__((ext_vector_type(2)));
typedef __fp16 fp16v2 __attribute__((ext_vector_type(2)));
typedef _Float16 f16x8 __attribute__((ext_vector_type(8)));
typedef float f32x4 __attribute__((ext_vector_type(4)));

__device__ __forceinline__ float dot2f(u32 a, u32 b, float c){
#if __has_builtin(__builtin_amdgcn_fdot2)
  h2 ha, hb; __builtin_memcpy(&ha, &a, 4); __builtin_memcpy(&hb, &b, 4);
  return __builtin_amdgcn_fdot2(ha, hb, c, false);
#else
  h2 ha, hb; __builtin_memcpy(&ha, &a, 4); __builtin_memcpy(&hb, &b, 4);
  return c + (float)ha[0]*(float)hb[0] + (float)ha[1]*(float)hb[1];
#endif
}
__device__ __forceinline__ u32 pkh2(float a, float b){
  fp16v2 r = __builtin_amdgcn_cvt_pkrtz(a, b);
  u32 u; __builtin_memcpy(&u, &r, 4); return u;
}
__device__ __forceinline__ u16 f2h(float f){ f16 h = (f16)f; u16 u; __builtin_memcpy(&u, &h, 2); return u; }
__device__ __forceinline__ float gelu_f(float x){ return 0.5f * x * (1.0f + erff(x * 0.70710678118654752440f)); }

// DPP wave64 sum -> valid in lane 63
__device__ __forceinline__ float wred(float v){
  int iv; float tf;
  #define DPPADD(CTRL, RMASK) \
    __builtin_memcpy(&iv, &v, 4); \
    iv = __builtin_amdgcn_update_dpp(0, iv, CTRL, RMASK, 0xf, true); \
    __builtin_memcpy(&tf, &iv, 4); \
    v += tf;
  DPPADD(0x111, 0xf)
  DPPADD(0x112, 0xf)
  DPPADD(0x114, 0xf)
  DPPADD(0x118, 0xf)
  DPPADD(0x142, 0xa)
  DPPADD(0x143, 0xc)
  #undef DPPADD
  return v;
}

// block-wide sum of (x,y) over 256 threads — enc/epi only
__device__ __forceinline__ void bsum2(float x, float y, float* red, int tid, float& ox, float& oy){
  #pragma unroll
  for (int off = 32; off >= 1; off >>= 1){ x += __shfl_xor(x, off); y += __shfl_xor(y, off); }
  __syncthreads();
  if ((tid & 63) == 0){ red[(tid >> 6)*2] = x; red[(tid >> 6)*2 + 1] = y; }
  __syncthreads();
  ox = red[0] + red[2] + red[4] + red[6];
  oy = red[1] + red[3] + red[5] + red[7];
}

// ---------------- prep: dxh (packed half2 dX), hb, gb ----------------
__global__ __launch_bounds__(128) void prep_misc(const float* __restrict__ path,
                                                 const float* __restrict__ ts,
                                                 const float* __restrict__ b3,
                                                 u32* __restrict__ dxh,
                                                 float* __restrict__ hb,
                                                 float* __restrict__ gb){
  const int b = blockIdx.x, tid = threadIdx.x;
  __shared__ float sdx[NSTEP * IND];
  for (int t = tid; t < NSTEP * IND; t += 128){
    int s = t >> 5, i = t & 31;
    float dt = ts[b*SS + s + 1] - ts[b*SS + s];
    sdx[t] = (path[(b*SS + s + 1)*IND + i] - path[(b*SS + s)*IND + i]) / dt;
  }
  if (tid < NSTEP) hb[b*NSTEP + tid] = ts[b*SS + tid + 1] - ts[b*SS + tid];
  __syncthreads();
  for (int t = tid; t < NSTEP * 16; t += 128){
    int s = t >> 4, i2 = t & 15;
    dxh[((size_t)b*NSTEP + s)*16 + i2] = pkh2(sdx[s*IND + 2*i2], sdx[s*IND + 2*i2 + 1]);
  }
  if (tid < HID){
    float w[IND];
    #pragma unroll
    for (int i = 0; i < IND; ++i) w[i] = b3[tid*IND + i];
    for (int s = 0; s < NSTEP; ++s){
      float a = 0.f;
      #pragma unroll
      for (int i = 0; i < IND; ++i) a = fmaf(w[i], sdx[s*IND + i], a);
      gb[(b*NSTEP + s)*HID + tid] = a;
    }
  }
}

// ---------------- pack vf_W3 (fp32) -> half2 pairs over i ----------------
__global__ __launch_bounds__(256) void pack_w3(const float* __restrict__ W3, u32* __restrict__ w3h){
  int i = blockIdx.x*256 + threadIdx.x;
  if (i < (HID2*HID*IND)/2) w3h[i] = pkh2(W3[2*i], W3[2*i + 1]);
}

// ---------------- pack W1/W2 into per-lane MFMA B-fragment order ----------------
// w1f: [w(4)][lane(64)][i16 = kt*4+nt (16)][q(4)] u32 = pack(W[k][col], W[k+1][col])
//   k = kt*32 + (lane>>4)*8 + 2q ; col = w*64 + nt*16 + (lane&15)
__global__ __launch_bounds__(256) void pack_wf(const float* __restrict__ W1,
                                               const float* __restrict__ W2,
                                               u32* __restrict__ w1f,
                                               u32* __restrict__ w2f){
  int i = blockIdx.x*256 + threadIdx.x;
  if (i < 16384){
    int lane_blk = i >> 6, rem = i & 63;
    int i16 = rem >> 2, q = rem & 3;
    int w = lane_blk >> 6, lane = lane_blk & 63;
    int kt = i16 >> 2, nt = i16 & 3;
    int k = kt*32 + (lane >> 4)*8 + 2*q;
    int col = w*64 + nt*16 + (lane & 15);
    w1f[i] = pkh2(W1[(size_t)k*HID2 + col], W1[(size_t)(k+1)*HID2 + col]);
  } else if (i < 16384 + 32768){
    int j = i - 16384;
    int lane_blk = j >> 7, rem = j & 127;
    int i32i = rem >> 2, q = rem & 3;
    int w = lane_blk >> 6, lane = lane_blk & 63;
    int kt = i32i >> 2, nt = i32i & 3;
    int k = kt*32 + (lane >> 4)*8 + 2*q;
    int col = w*64 + nt*16 + (lane & 15);
    w2f[j] = pkh2(W2[(size_t)k*HID2 + col], W2[(size_t)(k+1)*HID2 + col]);
  }
}

// ---------------- G in B-fragment layout ----------------
// Gp[(sl*BB+bb)*16384 + w*4096 + (kt*2+t)*256 + lane*4 + q]
//   = pack(G[k][h], G[k+1][h]),  k = kt*32 + (lane>>4)*8 + 2q, h = w*32 + t*16 + (lane&15)
__global__ __launch_bounds__(256) void gprep_h(const u32* __restrict__ w3h,
                                               const u32* __restrict__ dxh,
                                               u32* __restrict__ Gp, int s0){
  const int tid = threadIdx.x;
  const int sl = blockIdx.y; const int s = s0 + sl;
  const int lin = blockIdx.x*256 + tid;           // (kp, h)
  const int kp = lin >> 7, h = lin & 127;
  const uint4* wa = (const uint4*)(w3h + ((size_t)(2*kp)*HID + h)*16);
  const uint4* wb = (const uint4*)(w3h + ((size_t)(2*kp+1)*HID + h)*16);
  uint4 A0 = wa[0], A1 = wa[1], A2 = wa[2], A3 = wa[3];
  uint4 B0 = wb[0], B1 = wb[1], B2 = wb[2], B3 = wb[3];
  __shared__ u32 sdx[BB * 16];
  for (int t = tid; t < BB * 16; t += 256){
    int bb = t >> 4, i2 = t & 15;
    sdx[t] = dxh[((size_t)bb*NSTEP + s)*16 + i2];
  }
  __syncthreads();
  // fragment-layout output offset
  const int kt = kp >> 4, q = kp & 3, quad2 = (kp >> 2) & 3;
  const int wq = h >> 5, tq = (h >> 4) & 1, nn = h & 15;
  const size_t off = (size_t)wq*4096 + (size_t)(kt*2 + tq)*256 + (size_t)(quad2*16 + nn)*4 + q;
  const size_t base_sl = (size_t)sl * BB * 16384;
  for (int bb = 0; bb < BB; ++bb){
    const uint4* dp = (const uint4*)&sdx[bb*16];
    uint4 D0 = dp[0], D1 = dp[1], D2 = dp[2], D3 = dp[3];
    float g0 = 0.f, g1 = 0.f, g2 = 0.f, g3 = 0.f;
    g0 = dot2f(D0.x, A0.x, g0); g0 = dot2f(D0.y, A0.y, g0);
    g0 = dot2f(D0.z, A0.z, g0); g0 = dot2f(D0.w, A0.w, g0);
    g2 = dot2f(D1.x, A1.x, g2); g2 = dot2f(D1.y, A1.y, g2);
    g2 = dot2f(D1.z, A1.z, g2); g2 = dot2f(D1.w, A1.w, g2);
    g0 = dot2f(D2.x, A2.x, g0); g0 = dot2f(D2.y, A2.y, g0);
    g0 = dot2f(D2.z, A2.z, g0); g0 = dot2f(D2.w, A2.w, g0);
    g2 = dot2f(D3.x, A3.x, g2); g2 = dot2f(D3.y, A3.y, g2);
    g2 = dot2f(D3.z, A3.z, g2); g2 = dot2f(D3.w, A3.w, g2);
    g1 = dot2f(D0.x, B0.x, g1); g1 = dot2f(D0.y, B0.y, g1);
    g1 = dot2f(D0.z, B0.z, g1); g1 = dot2f(D0.w, B0.w, g1);
    g3 = dot2f(D1.x, B1.x, g3); g3 = dot2f(D1.y, B1.y, g3);
    g3 = dot2f(D1.z, B1.z, g3); g3 = dot2f(D1.w, B1.w, g3);
    g1 = dot2f(D2.x, B2.x, g1); g1 = dot2f(D2.y, B2.y, g1);
    g1 = dot2f(D2.z, B2.z, g1); g1 = dot2f(D2.w, B2.w, g1);
    g3 = dot2f(D3.x, B3.x, g3); g3 = dot2f(D3.y, B3.y, g3);
    g3 = dot2f(D3.z, B3.z, g3); g3 = dot2f(D3.w, B3.w, g3);
    Gp[base_sl + (size_t)bb*16384 + off] = pkh2(g0 + g2, g1 + g3);
  }
}

// ---------------- sequential RK4 scan: one block per batch element ----------------
struct ScanP {
  const float *path;
  const float *eW1,*eb1,*eg1,*ebt1,*eW2,*eb2,*eg2,*ebt2;
  const u32 *w1f, *w2f;
  const float *b1,*g1,*bt1,*b2,*g2,*bt2;
  const float *Wv,*bv,*Wo,*bo,*dW1,*db1,*dW2,*db2;
  const float *hb,*gb;
  const u32 *Gp;
  float *zstate, *out;
  int s0, s1, do_enc, do_epi;
};

__global__ __launch_bounds__(256, 1) void scan_kernel(ScanP p){
  const int tid = threadIdx.x;
  const int b = blockIdx.x;
  const int lane = tid & 63, w = tid >> 6;
  const int quad = lane >> 4, n16 = lane & 15;
  const bool owner = (quad == 0);
  __shared__ __align__(16) u16 zst_h[HID];
  __shared__ __align__(16) u16 a1p_h[HID2];
  __shared__ __align__(16) u16 a2p_h[HID2];
  __shared__ __align__(16) float red[8];
  __shared__ __align__(16) float zf[HID];
  __shared__ __align__(16) float sc1[HID2];

  // ---- persistent B-fragments: W1 (64 VGPR), W2 (128 VGPR) ----
  uint4 w1r[16], w2r[32];
  {
    const uint4* s1p = (const uint4*)p.w1f + ((size_t)(w*64 + lane))*16;
    #pragma unroll
    for (int i = 0; i < 16; ++i) w1r[i] = s1p[i];
    const uint4* s2p = (const uint4*)p.w2f + ((size_t)(w*64 + lane))*32;
    #pragma unroll
    for (int i = 0; i < 32; ++i) w2r[i] = s2p[i];
  }
  float rb1[4], rg1[4], rbt1[4], rb2[4], rg2[4], rbt2[4];
  #pragma unroll
  for (int nt = 0; nt < 4; ++nt){
    int col = w*64 + nt*16 + n16;
    rb1[nt] = p.b1[col]; rg1[nt] = p.g1[col]; rbt1[nt] = p.bt1[col];
    rb2[nt] = p.b2[col]; rg2[nt] = p.g2[col]; rbt2[nt] = p.bt2[col];
  }
  const int h0 = w*32 + n16, h1 = h0 + 16;

  float mu, sq;
  if (p.do_enc){
    if (tid < IND) sc1[tid] = p.path[(b*SS + 0)*IND + tid];
    __syncthreads();
    float acc = 0.f;
    if (tid < HID){
      acc = p.eb1[tid];
      #pragma unroll 8
      for (int i = 0; i < IND; ++i) acc = fmaf(sc1[i], p.eW1[i*HID + tid], acc);
    }
    float cx = (tid < HID) ? acc : 0.f;
    bsum2(cx, cx*cx, red, tid, mu, sq);
    mu *= (1.f/HID); float var = sq*(1.f/HID) - mu*mu; float rstd = rsqrtf(var + 1e-5f);
    if (tid < HID) zf[tid] = gelu_f((acc - mu)*rstd*p.eg1[tid] + p.ebt1[tid]);
    __syncthreads();
    float acc2 = 0.f;
    if (tid < HID){
      acc2 = p.eb2[tid];
      #pragma unroll 8
      for (int h = 0; h < HID; ++h) acc2 = fmaf(zf[h], p.eW2[h*HID + tid], acc2);
    }
    cx = (tid < HID) ? acc2 : 0.f;
    bsum2(cx, cx*cx, red, tid, mu, sq);
    mu *= (1.f/HID); float var2 = sq*(1.f/HID) - mu*mu; float rstd2 = rsqrtf(var2 + 1e-5f);
    __syncthreads();
    if (tid < HID) zf[tid] = (acc2 - mu)*rstd2*p.eg2[tid] + p.ebt2[tid];
    __syncthreads();
  }
  float zc0 = 0.f, zc1 = 0.f;
  if (owner){
    if (p.do_enc){ zc0 = zf[h0]; zc1 = zf[h1]; }
    else { zc0 = p.zstate[b*HID + h0]; zc1 = p.zstate[b*HID + h1]; }
  }

  for (int s = p.s0; s < p.s1; ++s){
    const float hbv = p.hb[b*NSTEP + s];
    // ---- G B-fragments for this step (64 VGPR), straight from global ----
    uint4 gr[16];
    {
      const uint4* g4 = (const uint4*)(p.Gp + ((size_t)(s - p.s0)*BB + b)*16384 + (size_t)w*4096);
      #pragma unroll
      for (int m = 0; m < 16; ++m) gr[m] = g4[m*64 + lane];
    }
    float gb0 = 0.f, gb1 = 0.f;
    if (owner){
      gb0 = p.gb[(b*NSTEP + s)*HID + h0];
      gb1 = p.gb[(b*NSTEP + s)*HID + h1];
      zst_h[h0] = f2h(zc0); zst_h[h1] = f2h(zc1);
    }
    float ks0 = 0.f, ks1 = 0.f;
    __syncthreads();

    #pragma unroll 1
    for (int st = 0; st < 4; ++st){
      // ---- layer1: D = zst(1x128) * W1(128x256), 16 MFMA ----
      f32x4 D0 = {0,0,0,0}, D1 = {0,0,0,0}, D2 = {0,0,0,0}, D3 = {0,0,0,0};
      {
        const uint4* za = (const uint4*)zst_h;
        #pragma unroll
        for (int kt = 0; kt < 4; ++kt){
          f16x8 a; uint4 av = za[kt*4 + quad]; __builtin_memcpy(&a, &av, 16);
          f16x8 bf;
          __builtin_memcpy(&bf, &w1r[kt*4+0], 16); D0 = __builtin_amdgcn_mfma_f32_16x16x32_f16(a, bf, D0, 0, 0, 0);
          __builtin_memcpy(&bf, &w1r[kt*4+1], 16); D1 = __builtin_amdgcn_mfma_f32_16x16x32_f16(a, bf, D1, 0, 0, 0);
          __builtin_memcpy(&bf, &w1r[kt*4+2], 16); D2 = __builtin_amdgcn_mfma_f32_16x16x32_f16(a, bf, D2, 0, 0, 0);
          __builtin_memcpy(&bf, &w1r[kt*4+3], 16); D3 = __builtin_amdgcn_mfma_f32_16x16x32_f16(a, bf, D3, 0, 0, 0);
        }
      }
      float v0 = D0[0] + rb1[0], v1 = D1[0] + rb1[1], v2 = D2[0] + rb1[2], v3 = D3[0] + rb1[3];
      float ssum = wred((v0 + v1) + (v2 + v3));
      float ssq  = wred((v0*v0 + v1*v1) + (v2*v2 + v3*v3));
      if (lane == 63){ red[w*2] = ssum; red[w*2+1] = ssq; }
      __syncthreads();                                    // b1
      {
        const float4* r4 = (const float4*)red;
        float4 ra = r4[0], rb = r4[1];
        float m1 = (ra.x + ra.z + rb.x + rb.z)*(1.f/1024.f);   // /4 replication /256
        float q1 = (ra.y + ra.w + rb.y + rb.w)*(1.f/1024.f);
        float rs1 = rsqrtf(q1 - m1*m1 + 1e-5f);
        if (owner){
          a1p_h[w*64 +  0 + n16] = f2h(gelu_f((v0 - m1)*rs1*rg1[0] + rbt1[0]));
          a1p_h[w*64 + 16 + n16] = f2h(gelu_f((v1 - m1)*rs1*rg1[1] + rbt1[1]));
          a1p_h[w*64 + 32 + n16] = f2h(gelu_f((v2 - m1)*rs1*rg1[2] + rbt1[2]));
          a1p_h[w*64 + 48 + n16] = f2h(gelu_f((v3 - m1)*rs1*rg1[3] + rbt1[3]));
        }
      }
      __syncthreads();                                    // b2
      // ---- layer2: D = a1(1x256) * W2(256x256), 32 MFMA ----
      D0 = {0,0,0,0}; D1 = {0,0,0,0}; D2 = {0,0,0,0}; D3 = {0,0,0,0};
      {
        const uint4* aa = (const uint4*)a1p_h;
        #pragma unroll
        for (int kt = 0; kt < 8; ++kt){
          f16x8 a; uint4 av = aa[kt*4 + quad]; __builtin_memcpy(&a, &av, 16);
          f16x8 bf;
          __builtin_memcpy(&bf, &w2r[kt*4+0], 16); D0 = __builtin_amdgcn_mfma_f32_16x16x32_f16(a, bf, D0, 0, 0, 0);
          __builtin_memcpy(&bf, &w2r[kt*4+1], 16); D1 = __builtin_amdgcn_mfma_f32_16x16x32_f16(a, bf, D1, 0, 0, 0);
          __builtin_memcpy(&bf, &w2r[kt*4+2], 16); D2 = __builtin_amdgcn_mfma_f32_16x16x32_f16(a, bf, D2, 0, 0, 0);
          __builtin_memcpy(&bf, &w2r[kt*4+3], 16); D3 = __builtin_amdgcn_mfma_f32_16x16x32_f16(a, bf, D3, 0, 0, 0);
        }
      }
      v0 = D0[0] + rb2[0]; v1 = D1[0] + rb2[1]; v2 = D2[0] + rb2[2]; v3 = D3[0] + rb2[3];
      ssum = wred((v0 + v1) + (v2 + v3));
      ssq  = wred((v0*v0 + v1*v1) + (v2*v2 + v3*v3));
      if (lane == 63){ red[w*2] = ssum; red[w*2+1] = ssq; }
      __syncthreads();                                    // b3
      {
        const float4* r4 = (const float4*)red;
        float4 ra = r4[0], rb = r4[1];
        float m2 = (ra.x + ra.z + rb.x + rb.z)*(1.f/1024.f);
        float q2 = (ra.y + ra.w + rb.y + rb.w)*(1.f/1024.f);
        float rs2 = rsqrtf(q2 - m2*m2 + 1e-5f);
        if (owner){
          a2p_h[w*64 +  0 + n16] = f2h(gelu_f((v0 - m2)*rs2*rg2[0] + rbt2[0]));
          a2p_h[w*64 + 16 + n16] = f2h(gelu_f((v1 - m2)*rs2*rg2[1] + rbt2[1]));
          a2p_h[w*64 + 32 + n16] = f2h(gelu_f((v2 - m2)*rs2*rg2[2] + rbt2[2]));
          a2p_h[w*64 + 48 + n16] = f2h(gelu_f((v3 - m2)*rs2*rg2[3] + rbt2[3]));
        }
      }
      __syncthreads();                                    // b4
      // ---- layer3: drift = a2(1x256) * G(256x128 slice of 32), 16 MFMA ----
      f32x4 E0 = {0,0,0,0}, E1 = {0,0,0,0};
      {
        const uint4* aa = (const uint4*)a2p_h;
        #pragma unroll
        for (int kt = 0; kt < 8; ++kt){
          f16x8 a; uint4 av = aa[kt*4 + quad]; __builtin_memcpy(&a, &av, 16);
          f16x8 g0f, g1f;
          __builtin_memcpy(&g0f, &gr[kt*2+0], 16);
          __builtin_memcpy(&g1f, &gr[kt*2+1], 16);
          E0 = __builtin_amdgcn_mfma_f32_16x16x32_f16(a, g0f, E0, 0, 0, 0);
          E1 = __builtin_amdgcn_mfma_f32_16x16x32_f16(a, g1f, E1, 0, 0, 0);
        }
      }
      if (owner){
        float kv0 = E0[0] + gb0, kv1 = E1[0] + gb1;
        float cst = (st == 0 || st == 3) ? 1.f : 2.f;
        ks0 += cst*kv0; ks1 += cst*kv1;
        if (st < 3){
          float c = (st == 2) ? hbv : 0.5f*hbv;
          zst_h[h0] = f2h(zc0 + c*kv0);
          zst_h[h1] = f2h(zc1 + c*kv1);
        }
      }
      __syncthreads();                                    // b5
    }
    if (owner){ zc0 += hbv*(1.f/6.f)*ks0; zc1 += hbv*(1.f/6.f)*ks1; }
  }

  if (p.do_epi){
    if (owner){ zf[h0] = zc0; zf[h1] = zc1; }
    __syncthreads();
    if (tid < HID){
      float v = p.bv[tid];
      #pragma unroll 8
      for (int h = 0; h < HID; ++h) v = fmaf(zf[h], p.Wv[h*HID + tid], v);
      sc1[tid] = v;
    }
    __syncthreads();
    if (tid < HID){
      float f = p.bo[tid];
      #pragma unroll 8
      for (int h = 0; h < HID; ++h) f = fmaf(sc1[h], p.Wo[h*HID + tid], f);
      sc1[HID + tid] = f;
    }
    __syncthreads();
    if (tid < HID){
      float hd = p.db1[tid];
      #pragma unroll 8
      for (int h = 0; h < HID; ++h) hd = fmaf(sc1[HID + h], p.dW1[h*HID + tid], hd);
      zf[tid] = gelu_f(hd);
    }
    __syncthreads();
    if (tid < 10){
      float t = p.db2[tid];
      #pragma unroll 8
      for (int h = 0; h < HID; ++h) t = fmaf(zf[h], p.dW2[h*10 + tid], t);
      p.out[b*10 + tid] = t;
    }
    if (tid == 0) p.out[BB*10 + b] = 1.0f;   // softmax over singleton axis == 1
  } else {
    if (owner){ p.zstate[b*HID + h0] = zc0; p.zstate[b*HID + h1] = zc1; }
  }
}

extern "C" void kernel_launch(void* const* d_in, const int* in_sizes, int n_in,
                              void* d_out, int out_size, void* d_ws, size_t ws_size,
                              hipStream_t stream){
  const float* path  = (const float*)d_in[0];
  const float* ts    = (const float*)d_in[1];
  const float* eW1   = (const float*)d_in[2];
  const float* eb1   = (const float*)d_in[3];
  const float* eg1   = (const float*)d_in[4];
  const float* ebt1  = (const float*)d_in[5];
  const float* eW2   = (const float*)d_in[6];
  const float* eb2   = (const float*)d_in[7];
  const float* eg2   = (const float*)d_in[8];
  const float* ebt2  = (const float*)d_in[9];
  const float* vW1   = (const float*)d_in[10];
  const float* vb1   = (const float*)d_in[11];
  const float* vg1   = (const float*)d_in[12];
  const float* vbt1  = (const float*)d_in[13];
  const float* vW2   = (const float*)d_in[14];
  const float* vb2   = (const float*)d_in[15];
  const float* vg2   = (const float*)d_in[16];
  const float* vbt2  = (const float*)d_in[17];
  const float* vW3   = (const float*)d_in[18];
  const float* vb3   = (const float*)d_in[19];
  const float* Wv    = (const float*)d_in[24];
  const float* bv    = (const float*)d_in[25];
  const float* Wo    = (const float*)d_in[26];
  const float* bo    = (const float*)d_in[27];
  const float* dW1   = (const float*)d_in[28];
  const float* db1   = (const float*)d_in[29];
  const float* dW2   = (const float*)d_in[30];
  const float* db2   = (const float*)d_in[31];

  char* wsb = (char*)d_ws;
  float* z_state = (float*)(wsb + 0);              // 64 KB
  u32*   dxh = (u32*)(wsb + 65536);                // 248 KB
  float* hb  = (float*)(wsb + 319488);             // 15.5 KB
  float* gb  = (float*)(wsb + 335872);             // 1.94 MB
  u32*   w3h = (u32*)(wsb + 2367488);              // 2 MB
  u32*   w1f = (u32*)(wsb + 4464640);              // 64 KB
  u32*   w2f = (u32*)(wsb + 4530176);              // 128 KB
  u32*   Gp  = (u32*)(wsb + 4661248);              // up to 248 MB

  hipLaunchKernelGGL(prep_misc, dim3(BB), dim3(128), 0, stream, path, ts, vb3, dxh, hb, gb);
  hipLaunchKernelGGL(pack_w3, dim3(2048), dim3(256), 0, stream, vW3, w3h);
  hipLaunchKernelGGL(pack_wf, dim3(192), dim3(256), 0, stream, vW1, vW2, w1f, w2f);

  const size_t per_step = (size_t)BB * 16384 * 4;  // 8 MB per step
  size_t gav = (ws_size > 4661248) ? (ws_size - 4661248) : per_step;
  int chunk = (int)(gav / per_step);
  if (chunk < 1) chunk = 1;
  if (chunk > NSTEP) chunk = NSTEP;

  for (int s0 = 0; s0 < NSTEP; s0 += chunk){
    int cs = (NSTEP - s0 < chunk) ? (NSTEP - s0) : chunk;
    hipLaunchKernelGGL(gprep_h, dim3(64, cs), dim3(256), 0, stream, w3h, dxh, Gp, s0);
    ScanP P;
    P.path = path;
    P.eW1 = eW1; P.eb1 = eb1; P.eg1 = eg1; P.ebt1 = ebt1;
    P.eW2 = eW2; P.eb2 = eb2; P.eg2 = eg2; P.ebt2 = ebt2;
    P.w1f = w1f; P.w2f = w2f;
    P.b1 = vb1; P.g1 = vg1; P.bt1 = vbt1;
    P.b2 = vb2; P.g2 = vg2; P.bt2 = vbt2;
    P.Wv = Wv; P.bv = bv; P.Wo = Wo; P.bo = bo;
    P.dW1 = dW1; P.db1 = db1; P.dW2 = dW2; P.db2 = db2;
    P.hb = hb; P.gb = gb; P.Gp = Gp;
    P.zstate = z_state; P.out = (float*)d_out;
    P.s0 = s0; P.s1 = s0 + cs;
    P.do_enc = (s0 == 0) ? 1 : 0;
    P.do_epi = (s0 + cs == NSTEP) ? 1 : 0;
    hipLaunchKernelGGL(scan_kernel, dim3(BB), dim3(256), 0, stream, P);
  }
}